// Round 1
// baseline (1597.060 us; speedup 1.0000x reference)
//
#include <hip/hip_runtime.h>

#define N_NODES 50000
#define N_EDGES 800000
#define D 128
#define ALPHA 0.2f
#define NEG_INF -1e30f

#define K1_BLOCKS 1024
#define K2_BLOCKS 512
#define K4_BLOCKS 8192

// K1: h = x @ W (fp32 vector), fused s1 = h@a1, s2 = h@a2.
// blockDim=128: thread j owns output column j; W[:,j] lives in 128 VGPRs.
// x broadcast across the wave via __shfl (compile-time lane -> v_readlane).
__global__ __launch_bounds__(128) void k_gemm(
    const float* __restrict__ x, const float* __restrict__ W,
    const float* __restrict__ a, float* __restrict__ h,
    float* __restrict__ s1, float* __restrict__ s2)
{
    const int j = threadIdx.x;        // column 0..127
    const int lane = j & 63;

    float Wreg[D];
    #pragma unroll
    for (int k = 0; k < D; ++k) Wreg[k] = W[k * D + j];
    const float a1j = a[j];
    const float a2j = a[D + j];

    for (int row = blockIdx.x; row < N_NODES; row += gridDim.x) {
        const float xa = x[row * D + lane];        // x[row][0..63] in wave regs
        const float xb = x[row * D + 64 + lane];   // x[row][64..127]
        float acc0 = 0.f, acc1 = 0.f, acc2 = 0.f, acc3 = 0.f;
        #pragma unroll
        for (int k = 0; k < 64; k += 4) {
            acc0 += __shfl(xa, k + 0) * Wreg[k + 0];
            acc1 += __shfl(xa, k + 1) * Wreg[k + 1];
            acc2 += __shfl(xa, k + 2) * Wreg[k + 2];
            acc3 += __shfl(xa, k + 3) * Wreg[k + 3];
        }
        #pragma unroll
        for (int k = 0; k < 64; k += 4) {
            acc0 += __shfl(xb, k + 0) * Wreg[64 + k + 0];
            acc1 += __shfl(xb, k + 1) * Wreg[64 + k + 1];
            acc2 += __shfl(xb, k + 2) * Wreg[64 + k + 2];
            acc3 += __shfl(xb, k + 3) * Wreg[64 + k + 3];
        }
        const float hv = (acc0 + acc1) + (acc2 + acc3);
        h[row * D + j] = hv;

        // wave-reduce hv*a1j, hv*a2j over 64 lanes; 2 waves -> atomic combine
        float v1 = hv * a1j;
        float v2 = hv * a2j;
        #pragma unroll
        for (int off = 32; off >= 1; off >>= 1) {
            v1 += __shfl_down(v1, off);
            v2 += __shfl_down(v2, off);
        }
        if (lane == 0) {
            atomicAdd(&s1[row], v1);
            atomicAdd(&s2[row], v2);
        }
    }
}

__device__ __forceinline__ void online_combine(float& m, float& s,
                                               float om, float os)
{
    float nm = fmaxf(m, om);
    s = s * __expf(m - nm) + os * __expf(om - nm);
    m = nm;
}

// K2: e = leaky_relu(s1[src]+s2[dst]); store e; per-block online (max, sumexp).
__global__ __launch_bounds__(256) void k_edge_pass1(
    const int* __restrict__ ei, const float* __restrict__ s1,
    const float* __restrict__ s2, float* __restrict__ ebuf,
    float* __restrict__ bm, float* __restrict__ bs)
{
    const int* src = ei;
    const int* dst = ei + N_EDGES;
    float m = NEG_INF, s = 0.f;
    for (int e = blockIdx.x * blockDim.x + threadIdx.x; e < N_EDGES;
         e += blockDim.x * gridDim.x) {
        float v = s1[src[e]] + s2[dst[e]];
        v = v > 0.f ? v : ALPHA * v;
        ebuf[e] = v;
        float nm = fmaxf(m, v);
        s = s * __expf(m - nm) + __expf(v - nm);
        m = nm;
    }
    #pragma unroll
    for (int off = 32; off >= 1; off >>= 1) {
        float om = __shfl_down(m, off);
        float os = __shfl_down(s, off);
        online_combine(m, s, om, os);
    }
    __shared__ float rm[4], rs[4];
    const int wid = threadIdx.x >> 6;
    if ((threadIdx.x & 63) == 0) { rm[wid] = m; rs[wid] = s; }
    __syncthreads();
    if (threadIdx.x == 0) {
        #pragma unroll
        for (int w = 1; w < 4; ++w) online_combine(m, s, rm[w], rs[w]);
        bm[blockIdx.x] = m;
        bs[blockIdx.x] = s;
    }
}

// K3: reduce per-block (m,s) -> global (M, Z)
__global__ __launch_bounds__(256) void k_reduce_mz(
    const float* __restrict__ bm, const float* __restrict__ bs,
    float* __restrict__ MZ)
{
    float m = NEG_INF, s = 0.f;
    for (int i = threadIdx.x; i < K2_BLOCKS; i += 256)
        online_combine(m, s, bm[i], bs[i]);
    #pragma unroll
    for (int off = 32; off >= 1; off >>= 1) {
        float om = __shfl_down(m, off);
        float os = __shfl_down(s, off);
        online_combine(m, s, om, os);
    }
    __shared__ float rm[4], rs[4];
    const int wid = threadIdx.x >> 6;
    if ((threadIdx.x & 63) == 0) { rm[wid] = m; rs[wid] = s; }
    __syncthreads();
    if (threadIdx.x == 0) {
        #pragma unroll
        for (int w = 1; w < 4; ++w) online_combine(m, s, rm[w], rs[w]);
        MZ[0] = m;
        MZ[1] = s;
    }
}

// K4: out[dst] += att * h[src], 32 lanes per edge, float4 per lane.
__global__ __launch_bounds__(256) void k_scatter(
    const int* __restrict__ ei, const float* __restrict__ ebuf,
    const float* __restrict__ h, const float* __restrict__ MZ,
    float* __restrict__ out)
{
    const int* src = ei;
    const int* dst = ei + N_EDGES;
    const float M = MZ[0];
    const float invZ = 1.0f / MZ[1];
    const int lane = threadIdx.x & 31;
    int g = (blockIdx.x * blockDim.x + threadIdx.x) >> 5;
    const int ng = (gridDim.x * blockDim.x) >> 5;
    for (int e = g; e < N_EDGES; e += ng) {
        const int sN = src[e];
        const int dN = dst[e];
        const float att = __expf(ebuf[e] - M) * invZ;
        const float4 hv = ((const float4*)(h + (size_t)sN * D))[lane];
        float* op = out + (size_t)dN * D + lane * 4;
        atomicAdd(op + 0, att * hv.x);
        atomicAdd(op + 1, att * hv.y);
        atomicAdd(op + 2, att * hv.z);
        atomicAdd(op + 3, att * hv.w);
    }
}

extern "C" void kernel_launch(void* const* d_in, const int* in_sizes, int n_in,
                              void* d_out, int out_size, void* d_ws, size_t ws_size,
                              hipStream_t stream)
{
    const float* x = (const float*)d_in[0];
    const float* W = (const float*)d_in[1];
    const float* a = (const float*)d_in[2];
    const int* ei = (const int*)d_in[3];
    float* out = (float*)d_out;

    float* ws = (float*)d_ws;
    float* h    = ws;                          // 6,400,000 floats
    float* s1   = h + (size_t)N_NODES * D;     // 50,000
    float* s2   = s1 + N_NODES;                // 50,000
    float* ebuf = s2 + N_NODES;                // 800,000
    float* bm   = ebuf + N_EDGES;              // K2_BLOCKS
    float* bs   = bm + K2_BLOCKS;              // K2_BLOCKS
    float* MZ   = bs + K2_BLOCKS;              // 2

    hipMemsetAsync(s1, 0, 2 * N_NODES * sizeof(float), stream);
    hipMemsetAsync(d_out, 0, (size_t)out_size * sizeof(float), stream);

    k_gemm<<<K1_BLOCKS, 128, 0, stream>>>(x, W, a, h, s1, s2);
    k_edge_pass1<<<K2_BLOCKS, 256, 0, stream>>>(ei, s1, s2, ebuf, bm, bs);
    k_reduce_mz<<<1, 256, 0, stream>>>(bm, bs, MZ);
    k_scatter<<<K4_BLOCKS, 256, 0, stream>>>(ei, ebuf, h, MZ, out);
}

// Round 2
// 486.747 us; speedup vs baseline: 3.2811x; 3.2811x over previous
//
#include <hip/hip_runtime.h>

#define N_NODES 50000
#define N_EDGES 800000
#define D 128
#define ALPHA 0.2f
#define NEG_INF -1e30f

#define K1_BLOCKS 1024
#define K2_BLOCKS 512
#define KB_BLOCKS 1024

// K1: h = x @ W (fp32 vector), fused s1 = h@a1, s2 = h@a2.
// blockDim=128: thread j owns output column j; W[:,j] lives in 128 VGPRs.
__global__ __launch_bounds__(128) void k_gemm(
    const float* __restrict__ x, const float* __restrict__ W,
    const float* __restrict__ a, float* __restrict__ h,
    float* __restrict__ s1, float* __restrict__ s2)
{
    const int j = threadIdx.x;        // column 0..127
    const int lane = j & 63;

    float Wreg[D];
    #pragma unroll
    for (int k = 0; k < D; ++k) Wreg[k] = W[k * D + j];
    const float a1j = a[j];
    const float a2j = a[D + j];

    for (int row = blockIdx.x; row < N_NODES; row += gridDim.x) {
        const float xa = x[row * D + lane];        // x[row][0..63]
        const float xb = x[row * D + 64 + lane];   // x[row][64..127]
        float acc0 = 0.f, acc1 = 0.f, acc2 = 0.f, acc3 = 0.f;
        #pragma unroll
        for (int k = 0; k < 64; k += 4) {
            acc0 += __shfl(xa, k + 0) * Wreg[k + 0];
            acc1 += __shfl(xa, k + 1) * Wreg[k + 1];
            acc2 += __shfl(xa, k + 2) * Wreg[k + 2];
            acc3 += __shfl(xa, k + 3) * Wreg[k + 3];
        }
        #pragma unroll
        for (int k = 0; k < 64; k += 4) {
            acc0 += __shfl(xb, k + 0) * Wreg[64 + k + 0];
            acc1 += __shfl(xb, k + 1) * Wreg[64 + k + 1];
            acc2 += __shfl(xb, k + 2) * Wreg[64 + k + 2];
            acc3 += __shfl(xb, k + 3) * Wreg[64 + k + 3];
        }
        const float hv = (acc0 + acc1) + (acc2 + acc3);
        h[row * D + j] = hv;

        float v1 = hv * a1j;
        float v2 = hv * a2j;
        #pragma unroll
        for (int off = 32; off >= 1; off >>= 1) {
            v1 += __shfl_down(v1, off);
            v2 += __shfl_down(v2, off);
        }
        if (lane == 0) {
            atomicAdd(&s1[row], v1);
            atomicAdd(&s2[row], v2);
        }
    }
}

__device__ __forceinline__ void online_combine(float& m, float& s,
                                               float om, float os)
{
    float nm = fmaxf(m, om);
    s = s * __expf(m - nm) + os * __expf(om - nm);
    m = nm;
}

// K2: per-block online (max, sumexp) of e = leaky_relu(s1[src]+s2[dst]);
// also counts in-degree of dst.
__global__ __launch_bounds__(256) void k_edge_pass1(
    const int* __restrict__ ei, const float* __restrict__ s1,
    const float* __restrict__ s2, int* __restrict__ deg,
    float* __restrict__ bm, float* __restrict__ bs)
{
    const int* src = ei;
    const int* dst = ei + N_EDGES;
    float m = NEG_INF, s = 0.f;
    for (int e = blockIdx.x * blockDim.x + threadIdx.x; e < N_EDGES;
         e += blockDim.x * gridDim.x) {
        const int dN = dst[e];
        float v = s1[src[e]] + s2[dN];
        v = v > 0.f ? v : ALPHA * v;
        atomicAdd(&deg[dN], 1);
        float nm = fmaxf(m, v);
        s = s * __expf(m - nm) + __expf(v - nm);
        m = nm;
    }
    #pragma unroll
    for (int off = 32; off >= 1; off >>= 1) {
        float om = __shfl_down(m, off);
        float os = __shfl_down(s, off);
        online_combine(m, s, om, os);
    }
    __shared__ float rm[4], rs[4];
    const int wid = threadIdx.x >> 6;
    if ((threadIdx.x & 63) == 0) { rm[wid] = m; rs[wid] = s; }
    __syncthreads();
    if (threadIdx.x == 0) {
        #pragma unroll
        for (int w = 1; w < 4; ++w) online_combine(m, s, rm[w], rs[w]);
        bm[blockIdx.x] = m;
        bs[blockIdx.x] = s;
    }
}

// K3: reduce per-block (m,s) -> global (M, Z)
__global__ __launch_bounds__(256) void k_reduce_mz(
    const float* __restrict__ bm, const float* __restrict__ bs,
    float* __restrict__ MZ)
{
    float m = NEG_INF, s = 0.f;
    for (int i = threadIdx.x; i < K2_BLOCKS; i += 256)
        online_combine(m, s, bm[i], bs[i]);
    #pragma unroll
    for (int off = 32; off >= 1; off >>= 1) {
        float om = __shfl_down(m, off);
        float os = __shfl_down(s, off);
        online_combine(m, s, om, os);
    }
    __shared__ float rm[4], rs[4];
    const int wid = threadIdx.x >> 6;
    if ((threadIdx.x & 63) == 0) { rm[wid] = m; rs[wid] = s; }
    __syncthreads();
    if (threadIdx.x == 0) {
        #pragma unroll
        for (int w = 1; w < 4; ++w) online_combine(m, s, rm[w], rs[w]);
        MZ[0] = m;
        MZ[1] = s;
    }
}

// K-scan: single block, exclusive scan of deg -> offs; cursor = offs copy.
__global__ __launch_bounds__(1024) void k_scan(
    const int* __restrict__ deg, int* __restrict__ offs,
    int* __restrict__ cursor)
{
    __shared__ int sums[1024];
    const int t = threadIdx.x;
    const int chunk = (N_NODES + 1023) / 1024;   // 49
    const int begin = t * chunk;
    const int end = min(begin + chunk, N_NODES);
    int s = 0;
    for (int i = begin; i < end && i < N_NODES; ++i) s += deg[i];
    sums[t] = s;
    __syncthreads();
    // Hillis-Steele inclusive scan over 1024 partials
    for (int off = 1; off < 1024; off <<= 1) {
        int v = (t >= off) ? sums[t - off] : 0;
        __syncthreads();
        sums[t] += v;
        __syncthreads();
    }
    int run = (t == 0) ? 0 : sums[t - 1];
    for (int i = begin; i < end && i < N_NODES; ++i) {
        offs[i] = run;
        cursor[i] = run;
        run += deg[i];
    }
    if (t == 1023) offs[N_NODES] = run;   // == N_EDGES
}

// K-bucket: scatter (src, e-score) pairs into dst-sorted CSR.
__global__ __launch_bounds__(256) void k_bucket(
    const int* __restrict__ ei, const float* __restrict__ s1,
    const float* __restrict__ s2, int* __restrict__ cursor,
    int2* __restrict__ csr)
{
    const int* src = ei;
    const int* dst = ei + N_EDGES;
    for (int e = blockIdx.x * blockDim.x + threadIdx.x; e < N_EDGES;
         e += blockDim.x * gridDim.x) {
        const int sN = src[e];
        const int dN = dst[e];
        float v = s1[sN] + s2[dN];
        v = v > 0.f ? v : ALPHA * v;
        const int pos = atomicAdd(&cursor[dN], 1);
        csr[pos] = make_int2(sN, __float_as_int(v));
    }
}

// K-gather: one 64-lane wave per dst node; lane accumulates float2 of the
// output row in registers over incoming edges. No atomics.
__global__ __launch_bounds__(256) void k_gather(
    const int2* __restrict__ csr, const int* __restrict__ offs,
    const float* __restrict__ h, const float* __restrict__ MZ,
    float* __restrict__ out)
{
    const int node = (blockIdx.x * blockDim.x + threadIdx.x) >> 6;
    if (node >= N_NODES) return;
    const int lane = threadIdx.x & 63;
    const float M = MZ[0];
    const float invZ = 1.0f / MZ[1];
    const int beg = offs[node];
    const int end = offs[node + 1];

    float2 acc0 = make_float2(0.f, 0.f);
    float2 acc1 = make_float2(0.f, 0.f);
    int i = beg;
    for (; i + 1 < end; i += 2) {
        const int2 p0 = csr[i];
        const int2 p1 = csr[i + 1];
        const float2 h0 = *(const float2*)(h + (size_t)p0.x * D + lane * 2);
        const float2 h1 = *(const float2*)(h + (size_t)p1.x * D + lane * 2);
        const float a0 = __expf(__int_as_float(p0.y) - M) * invZ;
        const float a1 = __expf(__int_as_float(p1.y) - M) * invZ;
        acc0.x += a0 * h0.x; acc0.y += a0 * h0.y;
        acc1.x += a1 * h1.x; acc1.y += a1 * h1.y;
    }
    if (i < end) {
        const int2 p0 = csr[i];
        const float2 h0 = *(const float2*)(h + (size_t)p0.x * D + lane * 2);
        const float a0 = __expf(__int_as_float(p0.y) - M) * invZ;
        acc0.x += a0 * h0.x; acc0.y += a0 * h0.y;
    }
    float2 r;
    r.x = acc0.x + acc1.x;
    r.y = acc0.y + acc1.y;
    *(float2*)(out + (size_t)node * D + lane * 2) = r;
}

extern "C" void kernel_launch(void* const* d_in, const int* in_sizes, int n_in,
                              void* d_out, int out_size, void* d_ws, size_t ws_size,
                              hipStream_t stream)
{
    const float* x = (const float*)d_in[0];
    const float* W = (const float*)d_in[1];
    const float* a = (const float*)d_in[2];
    const int* ei = (const int*)d_in[3];
    float* out = (float*)d_out;

    // workspace layout (4B units); csr first for 8B alignment
    char* wsb = (char*)d_ws;
    int2*  csr    = (int2*)wsb;                                  // 800,000 int2
    float* h      = (float*)(wsb + (size_t)N_EDGES * 8);         // 6,400,000
    float* s1     = h + (size_t)N_NODES * D;                     // 50,000
    float* s2     = s1 + N_NODES;                                // 50,000
    int*   deg    = (int*)(s2 + N_NODES);                        // 50,000
    int*   offs   = deg + N_NODES;                               // 50,001
    int*   cursor = offs + N_NODES + 1;                          // 50,000
    float* bm     = (float*)(cursor + N_NODES);                  // 512
    float* bs     = bm + K2_BLOCKS;                              // 512
    float* MZ     = bs + K2_BLOCKS;                              // 2

    hipMemsetAsync(s1, 0, 2 * N_NODES * sizeof(float), stream);
    hipMemsetAsync(deg, 0, N_NODES * sizeof(int), stream);

    k_gemm<<<K1_BLOCKS, 128, 0, stream>>>(x, W, a, h, s1, s2);
    k_edge_pass1<<<K2_BLOCKS, 256, 0, stream>>>(ei, s1, s2, deg, bm, bs);
    k_reduce_mz<<<1, 256, 0, stream>>>(bm, bs, MZ);
    k_scan<<<1, 1024, 0, stream>>>(deg, offs, cursor);
    k_bucket<<<KB_BLOCKS, 256, 0, stream>>>(ei, s1, s2, cursor, csr);
    // one wave per node: 50000 waves * 64 = 3.2M threads / 256 = 12500 blocks
    k_gather<<<(N_NODES * 64 + 255) / 256, 256, 0, stream>>>(csr, offs, h, MZ, out);
}

// Round 3
// 474.849 us; speedup vs baseline: 3.3633x; 1.0251x over previous
//
#include <hip/hip_runtime.h>
#include <hip/hip_bf16.h>

#define N_NODES 50000
#define N_EDGES 800000
#define D 128
#define ALPHA 0.2f
#define NEG_INF -1e30f

#define K1_BLOCKS 2048
#define K2_BLOCKS 512
#define KB_BLOCKS 1024

// K1: h = x @ W (fp32 vector), fused s1 = h@a1, s2 = h@a2, h stored as bf16.
// blockDim=128: thread j owns output column j; W[:,j] lives in 128 VGPRs.
// 2 rows per iteration (8-way FMA ILP) + software prefetch of next pair.
__global__ __launch_bounds__(128) void k_gemm(
    const float* __restrict__ x, const float* __restrict__ W,
    const float* __restrict__ a, __hip_bfloat16* __restrict__ hb,
    float* __restrict__ s1, float* __restrict__ s2)
{
    const int j = threadIdx.x;        // column 0..127
    const int lane = j & 63;

    float Wreg[D];
    #pragma unroll
    for (int k = 0; k < D; ++k) Wreg[k] = W[k * D + j];
    const float a1j = a[j];
    const float a2j = a[D + j];

    const int rstep = gridDim.x * 2;
    int r = blockIdx.x * 2;

    float xa0 = 0.f, xb0 = 0.f, xa1 = 0.f, xb1 = 0.f;
    if (r < N_NODES) {
        xa0 = x[(size_t)r * D + lane];
        xb0 = x[(size_t)r * D + 64 + lane];
        xa1 = x[(size_t)(r + 1) * D + lane];
        xb1 = x[(size_t)(r + 1) * D + 64 + lane];
    }

    while (r < N_NODES) {
        const int rn = r + rstep;
        float na0 = 0.f, nb0 = 0.f, na1 = 0.f, nb1 = 0.f;
        if (rn < N_NODES) {       // prefetch next pair (latency overlapped)
            na0 = x[(size_t)rn * D + lane];
            nb0 = x[(size_t)rn * D + 64 + lane];
            na1 = x[(size_t)(rn + 1) * D + lane];
            nb1 = x[(size_t)(rn + 1) * D + 64 + lane];
        }

        float p0 = 0.f, p1 = 0.f, p2 = 0.f, p3 = 0.f;
        float q0 = 0.f, q1 = 0.f, q2 = 0.f, q3 = 0.f;
        #pragma unroll
        for (int k = 0; k < 64; k += 4) {
            p0 += __shfl(xa0, k + 0) * Wreg[k + 0];
            q0 += __shfl(xa1, k + 0) * Wreg[k + 0];
            p1 += __shfl(xa0, k + 1) * Wreg[k + 1];
            q1 += __shfl(xa1, k + 1) * Wreg[k + 1];
            p2 += __shfl(xa0, k + 2) * Wreg[k + 2];
            q2 += __shfl(xa1, k + 2) * Wreg[k + 2];
            p3 += __shfl(xa0, k + 3) * Wreg[k + 3];
            q3 += __shfl(xa1, k + 3) * Wreg[k + 3];
        }
        #pragma unroll
        for (int k = 0; k < 64; k += 4) {
            p0 += __shfl(xb0, k + 0) * Wreg[64 + k + 0];
            q0 += __shfl(xb1, k + 0) * Wreg[64 + k + 0];
            p1 += __shfl(xb0, k + 1) * Wreg[64 + k + 1];
            q1 += __shfl(xb1, k + 1) * Wreg[64 + k + 1];
            p2 += __shfl(xb0, k + 2) * Wreg[64 + k + 2];
            q2 += __shfl(xb1, k + 2) * Wreg[64 + k + 2];
            p3 += __shfl(xb0, k + 3) * Wreg[64 + k + 3];
            q3 += __shfl(xb1, k + 3) * Wreg[64 + k + 3];
        }
        const float h0 = (p0 + p1) + (p2 + p3);
        const float h1 = (q0 + q1) + (q2 + q3);

        hb[(size_t)r * D + j]       = __float2bfloat16(h0);
        hb[(size_t)(r + 1) * D + j] = __float2bfloat16(h1);

        float v1 = h0 * a1j, v2 = h0 * a2j;
        float v3 = h1 * a1j, v4 = h1 * a2j;
        #pragma unroll
        for (int off = 32; off >= 1; off >>= 1) {
            v1 += __shfl_down(v1, off);
            v2 += __shfl_down(v2, off);
            v3 += __shfl_down(v3, off);
            v4 += __shfl_down(v4, off);
        }
        if (lane == 0) {
            atomicAdd(&s1[r], v1);
            atomicAdd(&s2[r], v2);
            atomicAdd(&s1[r + 1], v3);
            atomicAdd(&s2[r + 1], v4);
        }

        xa0 = na0; xb0 = nb0; xa1 = na1; xb1 = nb1;
        r = rn;
    }
}

__device__ __forceinline__ void online_combine(float& m, float& s,
                                               float om, float os)
{
    float nm = fmaxf(m, om);
    s = s * __expf(m - nm) + os * __expf(om - nm);
    m = nm;
}

// K2: per-block online (max, sumexp) of e = leaky_relu(s1[src]+s2[dst]);
// also counts in-degree of dst.
__global__ __launch_bounds__(256) void k_edge_pass1(
    const int* __restrict__ ei, const float* __restrict__ s1,
    const float* __restrict__ s2, int* __restrict__ deg,
    float* __restrict__ bm, float* __restrict__ bs)
{
    const int* src = ei;
    const int* dst = ei + N_EDGES;
    float m = NEG_INF, s = 0.f;
    for (int e = blockIdx.x * blockDim.x + threadIdx.x; e < N_EDGES;
         e += blockDim.x * gridDim.x) {
        const int dN = dst[e];
        float v = s1[src[e]] + s2[dN];
        v = v > 0.f ? v : ALPHA * v;
        atomicAdd(&deg[dN], 1);
        float nm = fmaxf(m, v);
        s = s * __expf(m - nm) + __expf(v - nm);
        m = nm;
    }
    #pragma unroll
    for (int off = 32; off >= 1; off >>= 1) {
        float om = __shfl_down(m, off);
        float os = __shfl_down(s, off);
        online_combine(m, s, om, os);
    }
    __shared__ float rm[4], rs[4];
    const int wid = threadIdx.x >> 6;
    if ((threadIdx.x & 63) == 0) { rm[wid] = m; rs[wid] = s; }
    __syncthreads();
    if (threadIdx.x == 0) {
        #pragma unroll
        for (int w = 1; w < 4; ++w) online_combine(m, s, rm[w], rs[w]);
        bm[blockIdx.x] = m;
        bs[blockIdx.x] = s;
    }
}

// K3: reduce per-block (m,s) -> global (M, Z)
__global__ __launch_bounds__(256) void k_reduce_mz(
    const float* __restrict__ bm, const float* __restrict__ bs,
    float* __restrict__ MZ)
{
    float m = NEG_INF, s = 0.f;
    for (int i = threadIdx.x; i < K2_BLOCKS; i += 256)
        online_combine(m, s, bm[i], bs[i]);
    #pragma unroll
    for (int off = 32; off >= 1; off >>= 1) {
        float om = __shfl_down(m, off);
        float os = __shfl_down(s, off);
        online_combine(m, s, om, os);
    }
    __shared__ float rm[4], rs[4];
    const int wid = threadIdx.x >> 6;
    if ((threadIdx.x & 63) == 0) { rm[wid] = m; rs[wid] = s; }
    __syncthreads();
    if (threadIdx.x == 0) {
        #pragma unroll
        for (int w = 1; w < 4; ++w) online_combine(m, s, rm[w], rs[w]);
        MZ[0] = m;
        MZ[1] = s;
    }
}

// K-scan: single block, exclusive scan of deg -> offs; cursor = offs copy.
__global__ __launch_bounds__(1024) void k_scan(
    const int* __restrict__ deg, int* __restrict__ offs,
    int* __restrict__ cursor)
{
    __shared__ int sums[1024];
    const int t = threadIdx.x;
    const int chunk = (N_NODES + 1023) / 1024;   // 49
    const int begin = t * chunk;
    const int end = min(begin + chunk, N_NODES);
    int s = 0;
    for (int i = begin; i < end && i < N_NODES; ++i) s += deg[i];
    sums[t] = s;
    __syncthreads();
    for (int off = 1; off < 1024; off <<= 1) {
        int v = (t >= off) ? sums[t - off] : 0;
        __syncthreads();
        sums[t] += v;
        __syncthreads();
    }
    int run = (t == 0) ? 0 : sums[t - 1];
    for (int i = begin; i < end && i < N_NODES; ++i) {
        offs[i] = run;
        cursor[i] = run;
        run += deg[i];
    }
    if (t == 1023) offs[N_NODES] = run;   // == N_EDGES
}

// K-bucket: scatter (src, e-score) pairs into dst-sorted CSR.
__global__ __launch_bounds__(256) void k_bucket(
    const int* __restrict__ ei, const float* __restrict__ s1,
    const float* __restrict__ s2, int* __restrict__ cursor,
    int2* __restrict__ csr)
{
    const int* src = ei;
    const int* dst = ei + N_EDGES;
    for (int e = blockIdx.x * blockDim.x + threadIdx.x; e < N_EDGES;
         e += blockDim.x * gridDim.x) {
        const int sN = src[e];
        const int dN = dst[e];
        float v = s1[sN] + s2[dN];
        v = v > 0.f ? v : ALPHA * v;
        const int pos = atomicAdd(&cursor[dN], 1);
        csr[pos] = make_int2(sN, __float_as_int(v));
    }
}

// K-gather: one 64-lane wave per dst node; lane accumulates 2 cols (bf16 h)
// in fp32 registers over incoming edges. No atomics.
__global__ __launch_bounds__(256) void k_gather(
    const int2* __restrict__ csr, const int* __restrict__ offs,
    const unsigned short* __restrict__ hb, const float* __restrict__ MZ,
    float* __restrict__ out)
{
    const int node = (blockIdx.x * blockDim.x + threadIdx.x) >> 6;
    if (node >= N_NODES) return;
    const int lane = threadIdx.x & 63;
    const float M = MZ[0];
    const float invZ = 1.0f / MZ[1];
    const int beg = offs[node];
    const int end = offs[node + 1];

    float a0 = 0.f, a1 = 0.f, b0 = 0.f, b1 = 0.f;
    int i = beg;
    for (; i + 1 < end; i += 2) {
        const int2 p0 = csr[i];
        const int2 p1 = csr[i + 1];
        const unsigned int u0 =
            *(const unsigned int*)(hb + (size_t)p0.x * D + lane * 2);
        const unsigned int u1 =
            *(const unsigned int*)(hb + (size_t)p1.x * D + lane * 2);
        const float w0 = __expf(__int_as_float(p0.y) - M) * invZ;
        const float w1 = __expf(__int_as_float(p1.y) - M) * invZ;
        a0 += w0 * __uint_as_float(u0 << 16);
        a1 += w0 * __uint_as_float(u0 & 0xFFFF0000u);
        b0 += w1 * __uint_as_float(u1 << 16);
        b1 += w1 * __uint_as_float(u1 & 0xFFFF0000u);
    }
    if (i < end) {
        const int2 p0 = csr[i];
        const unsigned int u0 =
            *(const unsigned int*)(hb + (size_t)p0.x * D + lane * 2);
        const float w0 = __expf(__int_as_float(p0.y) - M) * invZ;
        a0 += w0 * __uint_as_float(u0 << 16);
        a1 += w0 * __uint_as_float(u0 & 0xFFFF0000u);
    }
    float2 r;
    r.x = a0 + b0;
    r.y = a1 + b1;
    *(float2*)(out + (size_t)node * D + lane * 2) = r;
}

extern "C" void kernel_launch(void* const* d_in, const int* in_sizes, int n_in,
                              void* d_out, int out_size, void* d_ws, size_t ws_size,
                              hipStream_t stream)
{
    const float* x = (const float*)d_in[0];
    const float* W = (const float*)d_in[1];
    const float* a = (const float*)d_in[2];
    const int* ei = (const int*)d_in[3];
    float* out = (float*)d_out;

    // workspace layout; csr first for 8B alignment
    char* wsb = (char*)d_ws;
    int2* csr = (int2*)wsb;                                        // 6.4 MB
    __hip_bfloat16* hb = (__hip_bfloat16*)(wsb + (size_t)N_EDGES * 8); // 12.8 MB
    float* s1     = (float*)((char*)hb + (size_t)N_NODES * D * 2); // 50,000
    float* s2     = s1 + N_NODES;                                  // 50,000
    int*   deg    = (int*)(s2 + N_NODES);                          // 50,000
    int*   offs   = deg + N_NODES;                                 // 50,001
    int*   cursor = offs + N_NODES + 1;                            // 50,000
    float* bm     = (float*)(cursor + N_NODES);                    // 512
    float* bs     = bm + K2_BLOCKS;                                // 512
    float* MZ     = bs + K2_BLOCKS;                                // 2

    hipMemsetAsync(s1, 0, 2 * N_NODES * sizeof(float), stream);
    hipMemsetAsync(deg, 0, N_NODES * sizeof(int), stream);

    k_gemm<<<K1_BLOCKS, 128, 0, stream>>>(x, W, a, hb, s1, s2);
    k_edge_pass1<<<K2_BLOCKS, 256, 0, stream>>>(ei, s1, s2, deg, bm, bs);
    k_reduce_mz<<<1, 256, 0, stream>>>(bm, bs, MZ);
    k_scan<<<1, 1024, 0, stream>>>(deg, offs, cursor);
    k_bucket<<<KB_BLOCKS, 256, 0, stream>>>(ei, s1, s2, cursor, csr);
    k_gather<<<(N_NODES * 64 + 255) / 256, 256, 0, stream>>>(
        csr, offs, (const unsigned short*)hb, MZ, out);
}

// Round 4
// 360.057 us; speedup vs baseline: 4.4356x; 1.3188x over previous
//
#include <hip/hip_runtime.h>
#include <hip/hip_bf16.h>

#define N_NODES 50000
#define N_EDGES 800000
#define D 128
#define ALPHA 0.2f
#define NEG_INF -1e30f

#define K2_BLOCKS 512
#define KB_BLOCKS 1024

typedef __attribute__((ext_vector_type(8))) short short8;
typedef __attribute__((ext_vector_type(4))) float floatx4;

__device__ __forceinline__ unsigned short f2bf(float v)
{
    __hip_bfloat16 b = __float2bfloat16(v);
    return *reinterpret_cast<unsigned short*>(&b);
}

// ---- K0: w1 = W @ a1, w2 = W @ a2 (fp32, exact score factorization)
__global__ __launch_bounds__(128) void k_wprep(
    const float* __restrict__ W, const float* __restrict__ a,
    float* __restrict__ w1, float* __restrict__ w2)
{
    const int i = threadIdx.x;   // 0..127
    float acc1 = 0.f, acc2 = 0.f;
    #pragma unroll 8
    for (int j = 0; j < D; ++j) {
        const float wv = W[(size_t)i * D + j];
        acc1 += wv * a[j];
        acc2 += wv * a[D + j];
    }
    w1[i] = acc1;
    w2[i] = acc2;
}

// ---- K1a: xb = bf16(x); s1 = x@w1, s2 = x@w2 (fp32 exact). One wave per row.
__global__ __launch_bounds__(256) void k_cast(
    const float* __restrict__ x, const float* __restrict__ w1,
    const float* __restrict__ w2, unsigned short* __restrict__ xb,
    float* __restrict__ s1, float* __restrict__ s2)
{
    const int lane = threadIdx.x & 63;
    const int gw = (blockIdx.x * blockDim.x + threadIdx.x) >> 6;
    const int nw = (gridDim.x * blockDim.x) >> 6;
    const float w1a = w1[lane * 2], w1b = w1[lane * 2 + 1];
    const float w2a = w2[lane * 2], w2b = w2[lane * 2 + 1];
    for (int row = gw; row < N_NODES; row += nw) {
        const float2 v = *(const float2*)(x + (size_t)row * D + lane * 2);
        const unsigned int pack =
            (unsigned int)f2bf(v.x) | ((unsigned int)f2bf(v.y) << 16);
        *(unsigned int*)(xb + (size_t)row * D + lane * 2) = pack;
        float t1 = v.x * w1a + v.y * w1b;
        float t2 = v.x * w2a + v.y * w2b;
        #pragma unroll
        for (int off = 32; off >= 1; off >>= 1) {
            t1 += __shfl_down(t1, off);
            t2 += __shfl_down(t2, off);
        }
        if (lane == 0) { s1[row] = t1; s2[row] = t2; }
    }
}

// ---- K1b: hb = bf16(xb @ W) via MFMA 16x16x32 bf16.
// Wave w owns cols [32w, 32w+32): B frags (2 col-tiles x 4 k-steps) held in
// VGPRs, built once from fp32 W. A frags streamed from xb (16-row tiles).
// Layouts (verified, guide S3): A[m=lane&15][k=(lane>>4)*8+j],
// B[k=(lane>>4)*8+j][n=lane&15], C: col=lane&15, row=(lane>>4)*4+reg.
__global__ __launch_bounds__(256) void k_gemm_mfma(
    const unsigned short* __restrict__ xb, const float* __restrict__ W,
    unsigned short* __restrict__ hb)
{
    const int lane = threadIdx.x & 63;
    const int wv = threadIdx.x >> 6;      // wave 0..3
    const int q = lane >> 4;              // quad 0..3
    const int nIdx = lane & 15;
    const int n0 = wv * 32;

    short8 B[2][4];
    #pragma unroll
    for (int tile = 0; tile < 2; ++tile) {
        #pragma unroll
        for (int t = 0; t < 4; ++t) {
            short8 b;
            #pragma unroll
            for (int j = 0; j < 8; ++j) {
                const float v =
                    W[(size_t)(t * 32 + q * 8 + j) * D + n0 + tile * 16 + nIdx];
                b[j] = (short)f2bf(v);
            }
            B[tile][t] = b;
        }
    }

    for (int tileR = blockIdx.x; tileR < N_NODES / 16; tileR += gridDim.x) {
        const int rowbase = tileR * 16;
        const unsigned short* ap = xb + (size_t)(rowbase + nIdx) * D + q * 8;
        const short8 A0 = *(const short8*)(ap);
        const short8 A1 = *(const short8*)(ap + 32);
        const short8 A2 = *(const short8*)(ap + 64);
        const short8 A3 = *(const short8*)(ap + 96);

        floatx4 acc0 = {0.f, 0.f, 0.f, 0.f};
        floatx4 acc1 = {0.f, 0.f, 0.f, 0.f};
        acc0 = __builtin_amdgcn_mfma_f32_16x16x32_bf16(A0, B[0][0], acc0, 0, 0, 0);
        acc1 = __builtin_amdgcn_mfma_f32_16x16x32_bf16(A0, B[1][0], acc1, 0, 0, 0);
        acc0 = __builtin_amdgcn_mfma_f32_16x16x32_bf16(A1, B[0][1], acc0, 0, 0, 0);
        acc1 = __builtin_amdgcn_mfma_f32_16x16x32_bf16(A1, B[1][1], acc1, 0, 0, 0);
        acc0 = __builtin_amdgcn_mfma_f32_16x16x32_bf16(A2, B[0][2], acc0, 0, 0, 0);
        acc1 = __builtin_amdgcn_mfma_f32_16x16x32_bf16(A2, B[1][2], acc1, 0, 0, 0);
        acc0 = __builtin_amdgcn_mfma_f32_16x16x32_bf16(A3, B[0][3], acc0, 0, 0, 0);
        acc1 = __builtin_amdgcn_mfma_f32_16x16x32_bf16(A3, B[1][3], acc1, 0, 0, 0);

        #pragma unroll
        for (int i = 0; i < 4; ++i) {
            const int row = rowbase + q * 4 + i;
            hb[(size_t)row * D + n0 + nIdx]      = f2bf(acc0[i]);
            hb[(size_t)row * D + n0 + 16 + nIdx] = f2bf(acc1[i]);
        }
    }
}

__device__ __forceinline__ void online_combine(float& m, float& s,
                                               float om, float os)
{
    float nm = fmaxf(m, om);
    s = s * __expf(m - nm) + os * __expf(om - nm);
    m = nm;
}

// ---- K2: per-block online (max, sumexp) of e = leaky_relu(s1[src]+s2[dst]);
// also counts in-degree of dst.
__global__ __launch_bounds__(256) void k_edge_pass1(
    const int* __restrict__ ei, const float* __restrict__ s1,
    const float* __restrict__ s2, int* __restrict__ deg,
    float* __restrict__ bm, float* __restrict__ bs)
{
    const int* src = ei;
    const int* dst = ei + N_EDGES;
    float m = NEG_INF, s = 0.f;
    for (int e = blockIdx.x * blockDim.x + threadIdx.x; e < N_EDGES;
         e += blockDim.x * gridDim.x) {
        const int dN = dst[e];
        float v = s1[src[e]] + s2[dN];
        v = v > 0.f ? v : ALPHA * v;
        atomicAdd(&deg[dN], 1);
        float nm = fmaxf(m, v);
        s = s * __expf(m - nm) + __expf(v - nm);
        m = nm;
    }
    #pragma unroll
    for (int off = 32; off >= 1; off >>= 1) {
        float om = __shfl_down(m, off);
        float os = __shfl_down(s, off);
        online_combine(m, s, om, os);
    }
    __shared__ float rm[4], rs[4];
    const int wid = threadIdx.x >> 6;
    if ((threadIdx.x & 63) == 0) { rm[wid] = m; rs[wid] = s; }
    __syncthreads();
    if (threadIdx.x == 0) {
        #pragma unroll
        for (int w = 1; w < 4; ++w) online_combine(m, s, rm[w], rs[w]);
        bm[blockIdx.x] = m;
        bs[blockIdx.x] = s;
    }
}

// ---- K3: reduce per-block (m,s) -> global (M, Z)
__global__ __launch_bounds__(256) void k_reduce_mz(
    const float* __restrict__ bm, const float* __restrict__ bs,
    float* __restrict__ MZ)
{
    float m = NEG_INF, s = 0.f;
    for (int i = threadIdx.x; i < K2_BLOCKS; i += 256)
        online_combine(m, s, bm[i], bs[i]);
    #pragma unroll
    for (int off = 32; off >= 1; off >>= 1) {
        float om = __shfl_down(m, off);
        float os = __shfl_down(s, off);
        online_combine(m, s, om, os);
    }
    __shared__ float rm[4], rs[4];
    const int wid = threadIdx.x >> 6;
    if ((threadIdx.x & 63) == 0) { rm[wid] = m; rs[wid] = s; }
    __syncthreads();
    if (threadIdx.x == 0) {
        #pragma unroll
        for (int w = 1; w < 4; ++w) online_combine(m, s, rm[w], rs[w]);
        MZ[0] = m;
        MZ[1] = s;
    }
}

// ---- K-scan: single block, exclusive scan of deg -> offs; cursor copy.
__global__ __launch_bounds__(1024) void k_scan(
    const int* __restrict__ deg, int* __restrict__ offs,
    int* __restrict__ cursor)
{
    __shared__ int sums[1024];
    const int t = threadIdx.x;
    const int chunk = (N_NODES + 1023) / 1024;   // 49
    const int begin = t * chunk;
    const int end = min(begin + chunk, N_NODES);
    int s = 0;
    for (int i = begin; i < end && i < N_NODES; ++i) s += deg[i];
    sums[t] = s;
    __syncthreads();
    for (int off = 1; off < 1024; off <<= 1) {
        int v = (t >= off) ? sums[t - off] : 0;
        __syncthreads();
        sums[t] += v;
        __syncthreads();
    }
    int run = (t == 0) ? 0 : sums[t - 1];
    for (int i = begin; i < end && i < N_NODES; ++i) {
        offs[i] = run;
        cursor[i] = run;
        run += deg[i];
    }
    if (t == 1023) offs[N_NODES] = run;   // == N_EDGES
}

// ---- K-bucket: scatter (src, e-score) pairs into dst-sorted CSR.
__global__ __launch_bounds__(256) void k_bucket(
    const int* __restrict__ ei, const float* __restrict__ s1,
    const float* __restrict__ s2, int* __restrict__ cursor,
    int2* __restrict__ csr)
{
    const int* src = ei;
    const int* dst = ei + N_EDGES;
    for (int e = blockIdx.x * blockDim.x + threadIdx.x; e < N_EDGES;
         e += blockDim.x * gridDim.x) {
        const int sN = src[e];
        const int dN = dst[e];
        float v = s1[sN] + s2[dN];
        v = v > 0.f ? v : ALPHA * v;
        const int pos = atomicAdd(&cursor[dN], 1);
        csr[pos] = make_int2(sN, __float_as_int(v));
    }
}

// ---- K-gather: one 64-lane wave per dst node; fp32 accumulate of bf16 h.
__global__ __launch_bounds__(256) void k_gather(
    const int2* __restrict__ csr, const int* __restrict__ offs,
    const unsigned short* __restrict__ hb, const float* __restrict__ MZ,
    float* __restrict__ out)
{
    const int node = (blockIdx.x * blockDim.x + threadIdx.x) >> 6;
    if (node >= N_NODES) return;
    const int lane = threadIdx.x & 63;
    const float M = MZ[0];
    const float invZ = 1.0f / MZ[1];
    const int beg = offs[node];
    const int end = offs[node + 1];

    float a0 = 0.f, a1 = 0.f, b0 = 0.f, b1 = 0.f;
    int i = beg;
    for (; i + 1 < end; i += 2) {
        const int2 p0 = csr[i];
        const int2 p1 = csr[i + 1];
        const unsigned int u0 =
            *(const unsigned int*)(hb + (size_t)p0.x * D + lane * 2);
        const unsigned int u1 =
            *(const unsigned int*)(hb + (size_t)p1.x * D + lane * 2);
        const float w0 = __expf(__int_as_float(p0.y) - M) * invZ;
        const float w1 = __expf(__int_as_float(p1.y) - M) * invZ;
        a0 += w0 * __uint_as_float(u0 << 16);
        a1 += w0 * __uint_as_float(u0 & 0xFFFF0000u);
        b0 += w1 * __uint_as_float(u1 << 16);
        b1 += w1 * __uint_as_float(u1 & 0xFFFF0000u);
    }
    if (i < end) {
        const int2 p0 = csr[i];
        const unsigned int u0 =
            *(const unsigned int*)(hb + (size_t)p0.x * D + lane * 2);
        const float w0 = __expf(__int_as_float(p0.y) - M) * invZ;
        a0 += w0 * __uint_as_float(u0 << 16);
        a1 += w0 * __uint_as_float(u0 & 0xFFFF0000u);
    }
    float2 r;
    r.x = a0 + b0;
    r.y = a1 + b1;
    *(float2*)(out + (size_t)node * D + lane * 2) = r;
}

extern "C" void kernel_launch(void* const* d_in, const int* in_sizes, int n_in,
                              void* d_out, int out_size, void* d_ws, size_t ws_size,
                              hipStream_t stream)
{
    const float* x = (const float*)d_in[0];
    const float* W = (const float*)d_in[1];
    const float* a = (const float*)d_in[2];
    const int* ei = (const int*)d_in[3];
    float* out = (float*)d_out;

    // workspace layout; xb and csr share the first region (disjoint lifetimes:
    // xb dead after k_gemm_mfma, csr born in k_bucket).
    char* wsb = (char*)d_ws;
    unsigned short* xb = (unsigned short*)wsb;                     // 12.8 MB
    int2* csr = (int2*)wsb;                                        // 6.4 MB (union)
    unsigned short* hb = (unsigned short*)(wsb + (size_t)N_NODES * D * 2); // 12.8 MB
    float* s1     = (float*)((char*)hb + (size_t)N_NODES * D * 2); // 50,000
    float* s2     = s1 + N_NODES;                                  // 50,000
    int*   deg    = (int*)(s2 + N_NODES);                          // 50,000
    int*   offs   = deg + N_NODES;                                 // 50,001
    int*   cursor = offs + N_NODES + 1;                            // 50,000
    float* w1     = (float*)(cursor + N_NODES);                    // 128
    float* w2     = w1 + D;                                        // 128
    float* bm     = w2 + D;                                        // 512
    float* bs     = bm + K2_BLOCKS;                                // 512
    float* MZ     = bs + K2_BLOCKS;                                // 2

    hipMemsetAsync(deg, 0, N_NODES * sizeof(int), stream);

    k_wprep<<<1, 128, 0, stream>>>(W, a, w1, w2);
    k_cast<<<256, 256, 0, stream>>>(x, w1, w2, xb, s1, s2);
    k_gemm_mfma<<<512, 256, 0, stream>>>(xb, W, hb);
    k_edge_pass1<<<K2_BLOCKS, 256, 0, stream>>>(ei, s1, s2, deg, bm, bs);
    k_reduce_mz<<<1, 256, 0, stream>>>(bm, bs, MZ);
    k_scan<<<1, 1024, 0, stream>>>(deg, offs, cursor);
    k_bucket<<<KB_BLOCKS, 256, 0, stream>>>(ei, s1, s2, cursor, csr);
    k_gather<<<(N_NODES * 64 + 255) / 256, 256, 0, stream>>>(
        csr, offs, hb, MZ, out);
}

// Round 5
// 261.159 us; speedup vs baseline: 6.1153x; 1.3787x over previous
//
#include <hip/hip_runtime.h>
#include <hip/hip_bf16.h>

#define N_NODES 50000
#define N_EDGES 800000
#define D 128
#define ALPHA 0.2f
#define NEG_INF -1e30f

#define K2_BLOCKS 512
#define KB_BLOCKS 1024
#define NSCAN_BLOCKS ((N_NODES + 255) / 256)   // 196

typedef __attribute__((ext_vector_type(8))) short short8;
typedef __attribute__((ext_vector_type(4))) float floatx4;

__device__ __forceinline__ unsigned short f2bf(float v)
{
    __hip_bfloat16 b = __float2bfloat16(v);
    return *reinterpret_cast<unsigned short*>(&b);
}

// ---- K0: w1 = W @ a1, w2 = W @ a2 (fp32, exact score factorization)
__global__ __launch_bounds__(128) void k_wprep(
    const float* __restrict__ W, const float* __restrict__ a,
    float* __restrict__ w1, float* __restrict__ w2)
{
    const int i = threadIdx.x;   // 0..127
    float acc1 = 0.f, acc2 = 0.f;
    #pragma unroll 8
    for (int j = 0; j < D; ++j) {
        const float wv = W[(size_t)i * D + j];
        acc1 += wv * a[j];
        acc2 += wv * a[D + j];
    }
    w1[i] = acc1;
    w2[i] = acc2;
}

// ---- K1a: xb = bf16(x); s1 = x@w1, s2 = x@w2 (fp32 exact). One wave per row.
__global__ __launch_bounds__(256) void k_cast(
    const float* __restrict__ x, const float* __restrict__ w1,
    const float* __restrict__ w2, unsigned short* __restrict__ xb,
    float* __restrict__ s1, float* __restrict__ s2)
{
    const int lane = threadIdx.x & 63;
    const int gw = (blockIdx.x * blockDim.x + threadIdx.x) >> 6;
    const int nw = (gridDim.x * blockDim.x) >> 6;
    const float w1a = w1[lane * 2], w1b = w1[lane * 2 + 1];
    const float w2a = w2[lane * 2], w2b = w2[lane * 2 + 1];
    for (int row = gw; row < N_NODES; row += nw) {
        const float2 v = *(const float2*)(x + (size_t)row * D + lane * 2);
        const unsigned int pack =
            (unsigned int)f2bf(v.x) | ((unsigned int)f2bf(v.y) << 16);
        *(unsigned int*)(xb + (size_t)row * D + lane * 2) = pack;
        float t1 = v.x * w1a + v.y * w1b;
        float t2 = v.x * w2a + v.y * w2b;
        #pragma unroll
        for (int off = 32; off >= 1; off >>= 1) {
            t1 += __shfl_down(t1, off);
            t2 += __shfl_down(t2, off);
        }
        if (lane == 0) { s1[row] = t1; s2[row] = t2; }
    }
}

// ---- K1b: hb = bf16(xb @ W) via MFMA 16x16x32 bf16.
__global__ __launch_bounds__(256) void k_gemm_mfma(
    const unsigned short* __restrict__ xb, const float* __restrict__ W,
    unsigned short* __restrict__ hb)
{
    const int lane = threadIdx.x & 63;
    const int wv = threadIdx.x >> 6;      // wave 0..3
    const int q = lane >> 4;              // quad 0..3
    const int nIdx = lane & 15;
    const int n0 = wv * 32;

    short8 B[2][4];
    #pragma unroll
    for (int tile = 0; tile < 2; ++tile) {
        #pragma unroll
        for (int t = 0; t < 4; ++t) {
            short8 b;
            #pragma unroll
            for (int j = 0; j < 8; ++j) {
                const float v =
                    W[(size_t)(t * 32 + q * 8 + j) * D + n0 + tile * 16 + nIdx];
                b[j] = (short)f2bf(v);
            }
            B[tile][t] = b;
        }
    }

    for (int tileR = blockIdx.x; tileR < N_NODES / 16; tileR += gridDim.x) {
        const int rowbase = tileR * 16;
        const unsigned short* ap = xb + (size_t)(rowbase + nIdx) * D + q * 8;
        const short8 A0 = *(const short8*)(ap);
        const short8 A1 = *(const short8*)(ap + 32);
        const short8 A2 = *(const short8*)(ap + 64);
        const short8 A3 = *(const short8*)(ap + 96);

        floatx4 acc0 = {0.f, 0.f, 0.f, 0.f};
        floatx4 acc1 = {0.f, 0.f, 0.f, 0.f};
        acc0 = __builtin_amdgcn_mfma_f32_16x16x32_bf16(A0, B[0][0], acc0, 0, 0, 0);
        acc1 = __builtin_amdgcn_mfma_f32_16x16x32_bf16(A0, B[1][0], acc1, 0, 0, 0);
        acc0 = __builtin_amdgcn_mfma_f32_16x16x32_bf16(A1, B[0][1], acc0, 0, 0, 0);
        acc1 = __builtin_amdgcn_mfma_f32_16x16x32_bf16(A1, B[1][1], acc1, 0, 0, 0);
        acc0 = __builtin_amdgcn_mfma_f32_16x16x32_bf16(A2, B[0][2], acc0, 0, 0, 0);
        acc1 = __builtin_amdgcn_mfma_f32_16x16x32_bf16(A2, B[1][2], acc1, 0, 0, 0);
        acc0 = __builtin_amdgcn_mfma_f32_16x16x32_bf16(A3, B[0][3], acc0, 0, 0, 0);
        acc1 = __builtin_amdgcn_mfma_f32_16x16x32_bf16(A3, B[1][3], acc1, 0, 0, 0);

        #pragma unroll
        for (int i = 0; i < 4; ++i) {
            const int row = rowbase + q * 4 + i;
            hb[(size_t)row * D + n0 + nIdx]      = f2bf(acc0[i]);
            hb[(size_t)row * D + n0 + 16 + nIdx] = f2bf(acc1[i]);
        }
    }
}

__device__ __forceinline__ void online_combine(float& m, float& s,
                                               float om, float os)
{
    float nm = fmaxf(m, om);
    s = s * __expf(m - nm) + os * __expf(om - nm);
    m = nm;
}

// ---- K2: per-block online (max, sumexp) of e = leaky_relu(s1[src]+s2[dst]);
// also counts in-degree of dst.
__global__ __launch_bounds__(256) void k_edge_pass1(
    const int* __restrict__ ei, const float* __restrict__ s1,
    const float* __restrict__ s2, int* __restrict__ deg,
    float* __restrict__ bm, float* __restrict__ bs)
{
    const int* src = ei;
    const int* dst = ei + N_EDGES;
    float m = NEG_INF, s = 0.f;
    for (int e = blockIdx.x * blockDim.x + threadIdx.x; e < N_EDGES;
         e += blockDim.x * gridDim.x) {
        const int dN = dst[e];
        float v = s1[src[e]] + s2[dN];
        v = v > 0.f ? v : ALPHA * v;
        atomicAdd(&deg[dN], 1);
        float nm = fmaxf(m, v);
        s = s * __expf(m - nm) + __expf(v - nm);
        m = nm;
    }
    #pragma unroll
    for (int off = 32; off >= 1; off >>= 1) {
        float om = __shfl_down(m, off);
        float os = __shfl_down(s, off);
        online_combine(m, s, om, os);
    }
    __shared__ float rm[4], rs[4];
    const int wid = threadIdx.x >> 6;
    if ((threadIdx.x & 63) == 0) { rm[wid] = m; rs[wid] = s; }
    __syncthreads();
    if (threadIdx.x == 0) {
        #pragma unroll
        for (int w = 1; w < 4; ++w) online_combine(m, s, rm[w], rs[w]);
        bm[blockIdx.x] = m;
        bs[blockIdx.x] = s;
    }
}

// ---- K3: reduce per-block (m,s) -> global (M, Z)
__global__ __launch_bounds__(256) void k_reduce_mz(
    const float* __restrict__ bm, const float* __restrict__ bs,
    float* __restrict__ MZ)
{
    float m = NEG_INF, s = 0.f;
    for (int i = threadIdx.x; i < K2_BLOCKS; i += 256)
        online_combine(m, s, bm[i], bs[i]);
    #pragma unroll
    for (int off = 32; off >= 1; off >>= 1) {
        float om = __shfl_down(m, off);
        float os = __shfl_down(s, off);
        online_combine(m, s, om, os);
    }
    __shared__ float rm[4], rs[4];
    const int wid = threadIdx.x >> 6;
    if ((threadIdx.x & 63) == 0) { rm[wid] = m; rs[wid] = s; }
    __syncthreads();
    if (threadIdx.x == 0) {
        #pragma unroll
        for (int w = 1; w < 4; ++w) online_combine(m, s, rm[w], rs[w]);
        MZ[0] = m;
        MZ[1] = s;
    }
}

// ---- two-level scan: A) block sums, B) scan of partials, C) local scan+add
__global__ __launch_bounds__(256) void k_scan_a(
    const int* __restrict__ deg, int* __restrict__ partials)
{
    const int i = blockIdx.x * 256 + threadIdx.x;
    int v = (i < N_NODES) ? deg[i] : 0;
    #pragma unroll
    for (int off = 32; off >= 1; off >>= 1) v += __shfl_down(v, off);
    __shared__ int ws[4];
    if ((threadIdx.x & 63) == 0) ws[threadIdx.x >> 6] = v;
    __syncthreads();
    if (threadIdx.x == 0)
        partials[blockIdx.x] = ws[0] + ws[1] + ws[2] + ws[3];
}

__global__ __launch_bounds__(256) void k_scan_b(
    const int* __restrict__ partials, int* __restrict__ partialOffs,
    int* __restrict__ offs)
{
    __shared__ int sc[256];
    const int t = threadIdx.x;
    int v = (t < NSCAN_BLOCKS) ? partials[t] : 0;
    sc[t] = v;
    __syncthreads();
    #pragma unroll
    for (int off = 1; off < 256; off <<= 1) {
        int u = (t >= off) ? sc[t - off] : 0;
        __syncthreads();
        sc[t] += u;
        __syncthreads();
    }
    if (t < NSCAN_BLOCKS) partialOffs[t] = sc[t] - v;   // exclusive
    if (t == 255) offs[N_NODES] = sc[255];              // == N_EDGES
}

__global__ __launch_bounds__(256) void k_scan_c(
    const int* __restrict__ deg, const int* __restrict__ partialOffs,
    int* __restrict__ offs, int* __restrict__ cursor)
{
    __shared__ int sc[256];
    const int t = threadIdx.x;
    const int i = blockIdx.x * 256 + t;
    const int v = (i < N_NODES) ? deg[i] : 0;
    sc[t] = v;
    __syncthreads();
    #pragma unroll
    for (int off = 1; off < 256; off <<= 1) {
        int u = (t >= off) ? sc[t - off] : 0;
        __syncthreads();
        sc[t] += u;
        __syncthreads();
    }
    if (i < N_NODES) {
        const int o = partialOffs[blockIdx.x] + sc[t] - v;  // exclusive
        offs[i] = o;
        cursor[i] = o;
    }
}

// ---- K-bucket: scatter (src, e-score) pairs into dst-sorted CSR.
__global__ __launch_bounds__(256) void k_bucket(
    const int* __restrict__ ei, const float* __restrict__ s1,
    const float* __restrict__ s2, int* __restrict__ cursor,
    int2* __restrict__ csr)
{
    const int* src = ei;
    const int* dst = ei + N_EDGES;
    for (int e = blockIdx.x * blockDim.x + threadIdx.x; e < N_EDGES;
         e += blockDim.x * gridDim.x) {
        const int sN = src[e];
        const int dN = dst[e];
        float v = s1[sN] + s2[dN];
        v = v > 0.f ? v : ALPHA * v;
        const int pos = atomicAdd(&cursor[dN], 1);
        csr[pos] = make_int2(sN, __float_as_int(v));
    }
}

// ---- K-gather: one 64-lane wave per dst node; fp32 accumulate of bf16 h.
__global__ __launch_bounds__(256) void k_gather(
    const int2* __restrict__ csr, const int* __restrict__ offs,
    const unsigned short* __restrict__ hb, const float* __restrict__ MZ,
    float* __restrict__ out)
{
    const int node = (blockIdx.x * blockDim.x + threadIdx.x) >> 6;
    if (node >= N_NODES) return;
    const int lane = threadIdx.x & 63;
    const float M = MZ[0];
    const float invZ = 1.0f / MZ[1];
    const int beg = offs[node];
    const int end = offs[node + 1];

    float a0 = 0.f, a1 = 0.f, b0 = 0.f, b1 = 0.f;
    int i = beg;
    for (; i + 1 < end; i += 2) {
        const int2 p0 = csr[i];
        const int2 p1 = csr[i + 1];
        const unsigned int u0 =
            *(const unsigned int*)(hb + (size_t)p0.x * D + lane * 2);
        const unsigned int u1 =
            *(const unsigned int*)(hb + (size_t)p1.x * D + lane * 2);
        const float w0 = __expf(__int_as_float(p0.y) - M) * invZ;
        const float w1 = __expf(__int_as_float(p1.y) - M) * invZ;
        a0 += w0 * __uint_as_float(u0 << 16);
        a1 += w0 * __uint_as_float(u0 & 0xFFFF0000u);
        b0 += w1 * __uint_as_float(u1 << 16);
        b1 += w1 * __uint_as_float(u1 & 0xFFFF0000u);
    }
    if (i < end) {
        const int2 p0 = csr[i];
        const unsigned int u0 =
            *(const unsigned int*)(hb + (size_t)p0.x * D + lane * 2);
        const float w0 = __expf(__int_as_float(p0.y) - M) * invZ;
        a0 += w0 * __uint_as_float(u0 << 16);
        a1 += w0 * __uint_as_float(u0 & 0xFFFF0000u);
    }
    float2 r;
    r.x = a0 + b0;
    r.y = a1 + b1;
    *(float2*)(out + (size_t)node * D + lane * 2) = r;
}

extern "C" void kernel_launch(void* const* d_in, const int* in_sizes, int n_in,
                              void* d_out, int out_size, void* d_ws, size_t ws_size,
                              hipStream_t stream)
{
    const float* x = (const float*)d_in[0];
    const float* W = (const float*)d_in[1];
    const float* a = (const float*)d_in[2];
    const int* ei = (const int*)d_in[3];
    float* out = (float*)d_out;

    // workspace layout; xb and csr share the first region (disjoint lifetimes:
    // xb dead after k_gemm_mfma, csr born in k_bucket).
    char* wsb = (char*)d_ws;
    unsigned short* xb = (unsigned short*)wsb;                     // 12.8 MB
    int2* csr = (int2*)wsb;                                        // 6.4 MB (union)
    unsigned short* hb = (unsigned short*)(wsb + (size_t)N_NODES * D * 2); // 12.8 MB
    float* s1     = (float*)((char*)hb + (size_t)N_NODES * D * 2); // 50,000
    float* s2     = s1 + N_NODES;                                  // 50,000
    int*   deg    = (int*)(s2 + N_NODES);                          // 50,000
    int*   offs   = deg + N_NODES;                                 // 50,001
    int*   cursor = offs + N_NODES + 1;                            // 50,000
    int*   partials    = cursor + N_NODES;                         // 196
    int*   partialOffs = partials + NSCAN_BLOCKS;                  // 196
    float* w1     = (float*)(partialOffs + NSCAN_BLOCKS);          // 128
    float* w2     = w1 + D;                                        // 128
    float* bm     = w2 + D;                                        // 512
    float* bs     = bm + K2_BLOCKS;                                // 512
    float* MZ     = bs + K2_BLOCKS;                                // 2

    hipMemsetAsync(deg, 0, N_NODES * sizeof(int), stream);

    k_wprep<<<1, 128, 0, stream>>>(W, a, w1, w2);
    k_cast<<<256, 256, 0, stream>>>(x, w1, w2, xb, s1, s2);
    k_gemm_mfma<<<512, 256, 0, stream>>>(xb, W, hb);
    k_edge_pass1<<<K2_BLOCKS, 256, 0, stream>>>(ei, s1, s2, deg, bm, bs);
    k_reduce_mz<<<1, 256, 0, stream>>>(bm, bs, MZ);
    k_scan_a<<<NSCAN_BLOCKS, 256, 0, stream>>>(deg, partials);
    k_scan_b<<<1, 256, 0, stream>>>(partials, partialOffs, offs);
    k_scan_c<<<NSCAN_BLOCKS, 256, 0, stream>>>(deg, partialOffs, offs, cursor);
    k_bucket<<<KB_BLOCKS, 256, 0, stream>>>(ei, s1, s2, cursor, csr);
    k_gather<<<(N_NODES * 64 + 255) / 256, 256, 0, stream>>>(
        csr, offs, hb, MZ, out);
}

// Round 6
// 228.662 us; speedup vs baseline: 6.9844x; 1.1421x over previous
//
#include <hip/hip_runtime.h>
#include <hip/hip_bf16.h>

#define N_NODES 50000
#define N_EDGES 800000
#define D 128
#define ALPHA 0.2f
#define NEG_INF -1e30f

#define KC_BLOCKS 512
#define KB_BLOCKS 1024
#define NSCAN_BLOCKS ((N_NODES + 255) / 256)   // 196

typedef __attribute__((ext_vector_type(8))) short short8;
typedef __attribute__((ext_vector_type(4))) float floatx4;

__device__ __forceinline__ unsigned short f2bf(float v)
{
    __hip_bfloat16 b = __float2bfloat16(v);
    return *reinterpret_cast<unsigned short*>(&b);
}
__device__ __forceinline__ float bf_lo(unsigned int u)
{
    return __uint_as_float(u << 16);
}
__device__ __forceinline__ float bf_hi(unsigned int u)
{
    return __uint_as_float(u & 0xFFFF0000u);
}

// ---- K1: fused  (a) per-block w1=W@a1, w2=W@a2 into LDS (redundant, cheap)
//                 (b) xb = bf16(x); s1 = x@w1, s2 = x@w2 (fp32 exact)
//                 (c) in-degree count of dst
__global__ __launch_bounds__(256) void k_cast(
    const float* __restrict__ x, const float* __restrict__ W,
    const float* __restrict__ a, const int* __restrict__ ei,
    unsigned short* __restrict__ xb, float* __restrict__ s1,
    float* __restrict__ s2, int* __restrict__ deg)
{
    __shared__ float sw[2][D];
    {
        const int t = threadIdx.x;
        const int i = t & 127;
        const int which = t >> 7;             // 0 -> w1, 1 -> w2
        const float* av = a + which * D;
        float acc = 0.f;
        #pragma unroll 8
        for (int j = 0; j < D; ++j)
            acc += W[(size_t)i * D + j] * av[j];
        sw[which][i] = acc;
    }
    __syncthreads();

    const int lane = threadIdx.x & 63;
    const float w1a = sw[0][lane * 2], w1b = sw[0][lane * 2 + 1];
    const float w2a = sw[1][lane * 2], w2b = sw[1][lane * 2 + 1];
    const int gw = (blockIdx.x * blockDim.x + threadIdx.x) >> 6;
    const int nw = (gridDim.x * blockDim.x) >> 6;
    for (int row = gw; row < N_NODES; row += nw) {
        const float2 v = *(const float2*)(x + (size_t)row * D + lane * 2);
        const unsigned int pack =
            (unsigned int)f2bf(v.x) | ((unsigned int)f2bf(v.y) << 16);
        *(unsigned int*)(xb + (size_t)row * D + lane * 2) = pack;
        float t1 = v.x * w1a + v.y * w1b;
        float t2 = v.x * w2a + v.y * w2b;
        #pragma unroll
        for (int off = 32; off >= 1; off >>= 1) {
            t1 += __shfl_down(t1, off);
            t2 += __shfl_down(t2, off);
        }
        if (lane == 0) { s1[row] = t1; s2[row] = t2; }
    }

    // deg count (independent stream; overlaps with row-loop latency)
    const int gid = blockIdx.x * blockDim.x + threadIdx.x;
    const int nt = gridDim.x * blockDim.x;
    const int* dst = ei + N_EDGES;
    for (int e = gid; e < N_EDGES; e += nt)
        atomicAdd(&deg[dst[e]], 1);
}

// ---- K2: hb = bf16(xb @ W) via MFMA 16x16x32 bf16.
// Layouts (verified): A[m=lane&15][k=(lane>>4)*8+j],
// B[k=(lane>>4)*8+j][n=lane&15], C: col=lane&15, row=(lane>>4)*4+reg.
__global__ __launch_bounds__(256) void k_gemm_mfma(
    const unsigned short* __restrict__ xb, const float* __restrict__ W,
    unsigned short* __restrict__ hb)
{
    const int lane = threadIdx.x & 63;
    const int wv = threadIdx.x >> 6;      // wave 0..3
    const int q = lane >> 4;              // quad 0..3
    const int nIdx = lane & 15;
    const int n0 = wv * 32;

    short8 B[2][4];
    #pragma unroll
    for (int tile = 0; tile < 2; ++tile) {
        #pragma unroll
        for (int t = 0; t < 4; ++t) {
            short8 b;
            #pragma unroll
            for (int j = 0; j < 8; ++j) {
                const float v =
                    W[(size_t)(t * 32 + q * 8 + j) * D + n0 + tile * 16 + nIdx];
                b[j] = (short)f2bf(v);
            }
            B[tile][t] = b;
        }
    }

    for (int tileR = blockIdx.x; tileR < N_NODES / 16; tileR += gridDim.x) {
        const int rowbase = tileR * 16;
        const unsigned short* ap = xb + (size_t)(rowbase + nIdx) * D + q * 8;
        const short8 A0 = *(const short8*)(ap);
        const short8 A1 = *(const short8*)(ap + 32);
        const short8 A2 = *(const short8*)(ap + 64);
        const short8 A3 = *(const short8*)(ap + 96);

        floatx4 acc0 = {0.f, 0.f, 0.f, 0.f};
        floatx4 acc1 = {0.f, 0.f, 0.f, 0.f};
        acc0 = __builtin_amdgcn_mfma_f32_16x16x32_bf16(A0, B[0][0], acc0, 0, 0, 0);
        acc1 = __builtin_amdgcn_mfma_f32_16x16x32_bf16(A0, B[1][0], acc1, 0, 0, 0);
        acc0 = __builtin_amdgcn_mfma_f32_16x16x32_bf16(A1, B[0][1], acc0, 0, 0, 0);
        acc1 = __builtin_amdgcn_mfma_f32_16x16x32_bf16(A1, B[1][1], acc1, 0, 0, 0);
        acc0 = __builtin_amdgcn_mfma_f32_16x16x32_bf16(A2, B[0][2], acc0, 0, 0, 0);
        acc1 = __builtin_amdgcn_mfma_f32_16x16x32_bf16(A2, B[1][2], acc1, 0, 0, 0);
        acc0 = __builtin_amdgcn_mfma_f32_16x16x32_bf16(A3, B[0][3], acc0, 0, 0, 0);
        acc1 = __builtin_amdgcn_mfma_f32_16x16x32_bf16(A3, B[1][3], acc1, 0, 0, 0);

        #pragma unroll
        for (int i = 0; i < 4; ++i) {
            const int row = rowbase + q * 4 + i;
            hb[(size_t)row * D + n0 + nIdx]      = f2bf(acc0[i]);
            hb[(size_t)row * D + n0 + 16 + nIdx] = f2bf(acc1[i]);
        }
    }
}

__device__ __forceinline__ void online_combine(float& m, float& s,
                                               float om, float os)
{
    float nm = fmaxf(m, om);
    s = s * __expf(m - nm) + os * __expf(om - nm);
    m = nm;
}

// ---- two-level scan: A) block sums, B) scan of partials, C) local scan+add
__global__ __launch_bounds__(256) void k_scan_a(
    const int* __restrict__ deg, int* __restrict__ partials)
{
    const int i = blockIdx.x * 256 + threadIdx.x;
    int v = (i < N_NODES) ? deg[i] : 0;
    #pragma unroll
    for (int off = 32; off >= 1; off >>= 1) v += __shfl_down(v, off);
    __shared__ int ws[4];
    if ((threadIdx.x & 63) == 0) ws[threadIdx.x >> 6] = v;
    __syncthreads();
    if (threadIdx.x == 0)
        partials[blockIdx.x] = ws[0] + ws[1] + ws[2] + ws[3];
}

__global__ __launch_bounds__(256) void k_scan_b(
    const int* __restrict__ partials, int* __restrict__ partialOffs,
    int* __restrict__ offs)
{
    __shared__ int sc[256];
    const int t = threadIdx.x;
    int v = (t < NSCAN_BLOCKS) ? partials[t] : 0;
    sc[t] = v;
    __syncthreads();
    #pragma unroll
    for (int off = 1; off < 256; off <<= 1) {
        int u = (t >= off) ? sc[t - off] : 0;
        __syncthreads();
        sc[t] += u;
        __syncthreads();
    }
    if (t < NSCAN_BLOCKS) partialOffs[t] = sc[t] - v;   // exclusive
    if (t == 255) offs[N_NODES] = sc[255];              // == N_EDGES
}

__global__ __launch_bounds__(256) void k_scan_c(
    const int* __restrict__ deg, const int* __restrict__ partialOffs,
    int* __restrict__ offs, int* __restrict__ cursor)
{
    __shared__ int sc[256];
    const int t = threadIdx.x;
    const int i = blockIdx.x * 256 + t;
    const int v = (i < N_NODES) ? deg[i] : 0;
    sc[t] = v;
    __syncthreads();
    #pragma unroll
    for (int off = 1; off < 256; off <<= 1) {
        int u = (t >= off) ? sc[t - off] : 0;
        __syncthreads();
        sc[t] += u;
        __syncthreads();
    }
    if (i < N_NODES) {
        const int o = partialOffs[blockIdx.x] + sc[t] - v;  // exclusive
        offs[i] = o;
        cursor[i] = o;
    }
}

// ---- K-bucket: scatter (src, e-score) into dst-sorted CSR, fused with the
// global online-softmax (m, sumexp) block reduction.
__global__ __launch_bounds__(256) void k_bucket(
    const int* __restrict__ ei, const float* __restrict__ s1,
    const float* __restrict__ s2, int* __restrict__ cursor,
    int2* __restrict__ csr, float* __restrict__ bm, float* __restrict__ bs)
{
    const int* src = ei;
    const int* dst = ei + N_EDGES;
    float m = NEG_INF, s = 0.f;
    for (int e = blockIdx.x * blockDim.x + threadIdx.x; e < N_EDGES;
         e += blockDim.x * gridDim.x) {
        const int sN = src[e];
        const int dN = dst[e];
        float v = s1[sN] + s2[dN];
        v = v > 0.f ? v : ALPHA * v;
        const int pos = atomicAdd(&cursor[dN], 1);
        csr[pos] = make_int2(sN, __float_as_int(v));
        float nm = fmaxf(m, v);
        s = s * __expf(m - nm) + __expf(v - nm);
        m = nm;
    }
    #pragma unroll
    for (int off = 32; off >= 1; off >>= 1) {
        float om = __shfl_down(m, off);
        float os = __shfl_down(s, off);
        online_combine(m, s, om, os);
    }
    __shared__ float rm[4], rs[4];
    const int wid = threadIdx.x >> 6;
    if ((threadIdx.x & 63) == 0) { rm[wid] = m; rs[wid] = s; }
    __syncthreads();
    if (threadIdx.x == 0) {
        #pragma unroll
        for (int w = 1; w < 4; ++w) online_combine(m, s, rm[w], rs[w]);
        bm[blockIdx.x] = m;
        bs[blockIdx.x] = s;
    }
}

// ---- reduce per-block (m,s) -> global (M, Z)
__global__ __launch_bounds__(256) void k_reduce_mz(
    const float* __restrict__ bm, const float* __restrict__ bs,
    float* __restrict__ MZ)
{
    float m = NEG_INF, s = 0.f;
    for (int i = threadIdx.x; i < KB_BLOCKS; i += 256)
        online_combine(m, s, bm[i], bs[i]);
    #pragma unroll
    for (int off = 32; off >= 1; off >>= 1) {
        float om = __shfl_down(m, off);
        float os = __shfl_down(s, off);
        online_combine(m, s, om, os);
    }
    __shared__ float rm[4], rs[4];
    const int wid = threadIdx.x >> 6;
    if ((threadIdx.x & 63) == 0) { rm[wid] = m; rs[wid] = s; }
    __syncthreads();
    if (threadIdx.x == 0) {
        #pragma unroll
        for (int w = 1; w < 4; ++w) online_combine(m, s, rm[w], rs[w]);
        MZ[0] = m;
        MZ[1] = s;
    }
}

// ---- K-gather: one wave per dst node. Each lane loads ONE csr entry
// (coalesced) and computes ONE exp; inner loop broadcasts (src, att) via
// uniform-index shfl (readlane) and keeps 4 hb row loads in flight.
__global__ __launch_bounds__(256) void k_gather(
    const int2* __restrict__ csr, const int* __restrict__ offs,
    const unsigned short* __restrict__ hb, const float* __restrict__ MZ,
    float* __restrict__ out)
{
    const int node = (blockIdx.x * blockDim.x + threadIdx.x) >> 6;
    if (node >= N_NODES) return;
    const int lane = threadIdx.x & 63;
    const float M = MZ[0];
    const float invZ = 1.0f / MZ[1];
    const int beg = offs[node];
    const int end = offs[node + 1];

    float a0 = 0.f, a1 = 0.f, b0 = 0.f, b1 = 0.f;
    float c0 = 0.f, c1 = 0.f, d0 = 0.f, d1 = 0.f;

    for (int cb = beg; cb < end; cb += 64) {
        const int n = min(64, end - cb);
        int2 p = make_int2(0, __float_as_int(NEG_INF));
        if (cb + lane < end) p = csr[cb + lane];
        const int srcl = p.x;
        const float attl = __expf(__int_as_float(p.y) - M) * invZ;

        int j = 0;
        for (; j + 3 < n; j += 4) {
            const int i0 = __shfl(srcl, j);
            const int i1 = __shfl(srcl, j + 1);
            const int i2 = __shfl(srcl, j + 2);
            const int i3 = __shfl(srcl, j + 3);
            const float w0 = __shfl(attl, j);
            const float w1 = __shfl(attl, j + 1);
            const float w2 = __shfl(attl, j + 2);
            const float w3 = __shfl(attl, j + 3);
            const unsigned int u0 =
                *(const unsigned int*)(hb + (size_t)i0 * D + lane * 2);
            const unsigned int u1 =
                *(const unsigned int*)(hb + (size_t)i1 * D + lane * 2);
            const unsigned int u2 =
                *(const unsigned int*)(hb + (size_t)i2 * D + lane * 2);
            const unsigned int u3 =
                *(const unsigned int*)(hb + (size_t)i3 * D + lane * 2);
            a0 += w0 * bf_lo(u0); a1 += w0 * bf_hi(u0);
            b0 += w1 * bf_lo(u1); b1 += w1 * bf_hi(u1);
            c0 += w2 * bf_lo(u2); c1 += w2 * bf_hi(u2);
            d0 += w3 * bf_lo(u3); d1 += w3 * bf_hi(u3);
        }
        for (; j < n; ++j) {
            const int i0 = __shfl(srcl, j);
            const float w0 = __shfl(attl, j);
            const unsigned int u0 =
                *(const unsigned int*)(hb + (size_t)i0 * D + lane * 2);
            a0 += w0 * bf_lo(u0); a1 += w0 * bf_hi(u0);
        }
    }
    float2 r;
    r.x = (a0 + b0) + (c0 + d0);
    r.y = (a1 + b1) + (c1 + d1);
    *(float2*)(out + (size_t)node * D + lane * 2) = r;
}

extern "C" void kernel_launch(void* const* d_in, const int* in_sizes, int n_in,
                              void* d_out, int out_size, void* d_ws, size_t ws_size,
                              hipStream_t stream)
{
    const float* x = (const float*)d_in[0];
    const float* W = (const float*)d_in[1];
    const float* a = (const float*)d_in[2];
    const int* ei = (const int*)d_in[3];
    float* out = (float*)d_out;

    // workspace layout; xb and csr share the first region (disjoint lifetimes:
    // xb dead after k_gemm_mfma, csr born in k_bucket).
    char* wsb = (char*)d_ws;
    unsigned short* xb = (unsigned short*)wsb;                     // 12.8 MB
    int2* csr = (int2*)wsb;                                        // 6.4 MB (union)
    unsigned short* hb = (unsigned short*)(wsb + (size_t)N_NODES * D * 2); // 12.8 MB
    float* s1     = (float*)((char*)hb + (size_t)N_NODES * D * 2); // 50,000
    float* s2     = s1 + N_NODES;                                  // 50,000
    int*   deg    = (int*)(s2 + N_NODES);                          // 50,000
    int*   offs   = deg + N_NODES;                                 // 50,001
    int*   cursor = offs + N_NODES + 1;                            // 50,000
    int*   partials    = cursor + N_NODES;                         // 196
    int*   partialOffs = partials + NSCAN_BLOCKS;                  // 196
    float* bm     = (float*)(partialOffs + NSCAN_BLOCKS);          // 1024
    float* bs     = bm + KB_BLOCKS;                                // 1024
    float* MZ     = bs + KB_BLOCKS;                                // 2

    hipMemsetAsync(deg, 0, N_NODES * sizeof(int), stream);

    k_cast<<<KC_BLOCKS, 256, 0, stream>>>(x, W, a, ei, xb, s1, s2, deg);
    k_gemm_mfma<<<512, 256, 0, stream>>>(xb, W, hb);
    k_scan_a<<<NSCAN_BLOCKS, 256, 0, stream>>>(deg, partials);
    k_scan_b<<<1, 256, 0, stream>>>(partials, partialOffs, offs);
    k_scan_c<<<NSCAN_BLOCKS, 256, 0, stream>>>(deg, partialOffs, offs, cursor);
    k_bucket<<<KB_BLOCKS, 256, 0, stream>>>(ei, s1, s2, cursor, csr, bm, bs);
    k_reduce_mz<<<1, 256, 0, stream>>>(bm, bs, MZ);
    k_gather<<<(N_NODES * 64 + 255) / 256, 256, 0, stream>>>(
        csr, offs, hb, MZ, out);
}

// Round 7
// 221.718 us; speedup vs baseline: 7.2031x; 1.0313x over previous
//
#include <hip/hip_runtime.h>
#include <hip/hip_bf16.h>

#define N_NODES 50000
#define N_EDGES 800000
#define D 128
#define ALPHA 0.2f
#define NEG_INF -1e30f

#define KC_BLOCKS 3125            // 4 waves x 4 rows = 16 rows/block, exact
#define KB_BLOCKS 1024
#define NSCAN_BLOCKS ((N_NODES + 255) / 256)   // 196

typedef __attribute__((ext_vector_type(8))) short short8;
typedef __attribute__((ext_vector_type(4))) float floatx4;

__device__ __forceinline__ unsigned int f2bf(float v)
{
    __hip_bfloat16 b = __float2bfloat16(v);
    return (unsigned int)*reinterpret_cast<unsigned short*>(&b);
}
__device__ __forceinline__ float bf_lo(unsigned int u)
{
    return __uint_as_float(u << 16);
}
__device__ __forceinline__ float bf_hi(unsigned int u)
{
    return __uint_as_float(u & 0xFFFF0000u);
}

// ---- K0: w12[0:128)=W@a1, w12[128:256)=W@a2 (fp32, exact factorization)
__global__ __launch_bounds__(256) void k_wprep(
    const float* __restrict__ W, const float* __restrict__ a,
    float* __restrict__ w12)
{
    const int t = threadIdx.x;
    const int i = t & 127;
    const int which = t >> 7;
    const float* av = a + which * D;
    float acc = 0.f;
    #pragma unroll 8
    for (int j = 0; j < D; ++j)
        acc += W[(size_t)i * D + j] * av[j];
    w12[which * D + i] = acc;
}

// ---- K1: xb = bf16(x); s1 = x@w1, s2 = x@w2 (fp32 exact).
// One wave = 4 rows; 3125 blocks -> full TLP; 8 interleaved shfl chains.
__global__ __launch_bounds__(256) void k_cast(
    const float* __restrict__ x, const float* __restrict__ w12,
    unsigned short* __restrict__ xb, float* __restrict__ s1,
    float* __restrict__ s2)
{
    const int lane = threadIdx.x & 63;
    const int wid = threadIdx.x >> 6;
    const int base = (blockIdx.x * 4 + wid) * 4;
    const float w1a = w12[lane * 2], w1b = w12[lane * 2 + 1];
    const float w2a = w12[D + lane * 2], w2b = w12[D + lane * 2 + 1];

    float t1[4], t2[4];
    #pragma unroll
    for (int rr = 0; rr < 4; ++rr) {
        const int row = base + rr;
        const float2 v = *(const float2*)(x + (size_t)row * D + lane * 2);
        const unsigned int pack = f2bf(v.x) | (f2bf(v.y) << 16);
        *(unsigned int*)(xb + (size_t)row * D + lane * 2) = pack;
        t1[rr] = v.x * w1a + v.y * w1b;
        t2[rr] = v.x * w2a + v.y * w2b;
    }
    #pragma unroll
    for (int off = 32; off >= 1; off >>= 1) {
        #pragma unroll
        for (int rr = 0; rr < 4; ++rr) {
            t1[rr] += __shfl_down(t1[rr], off);
            t2[rr] += __shfl_down(t2[rr], off);
        }
    }
    if (lane == 0) {
        #pragma unroll
        for (int rr = 0; rr < 4; ++rr) {
            s1[base + rr] = t1[rr];
            s2[base + rr] = t2[rr];
        }
    }
}

// ---- K2: hb = bf16(xb @ W) via MFMA 16x16x32 bf16; deg-count fused in tail
// (atomics overlap the MFMA drain across waves).
__global__ __launch_bounds__(256) void k_gemm_mfma(
    const unsigned short* __restrict__ xb, const float* __restrict__ W,
    unsigned short* __restrict__ hb, const int* __restrict__ ei,
    int* __restrict__ deg)
{
    const int lane = threadIdx.x & 63;
    const int wv = threadIdx.x >> 6;      // wave 0..3
    const int q = lane >> 4;              // quad 0..3
    const int nIdx = lane & 15;
    const int n0 = wv * 32;

    short8 B[2][4];
    #pragma unroll
    for (int tile = 0; tile < 2; ++tile) {
        #pragma unroll
        for (int t = 0; t < 4; ++t) {
            short8 b;
            #pragma unroll
            for (int j = 0; j < 8; ++j) {
                const float v =
                    W[(size_t)(t * 32 + q * 8 + j) * D + n0 + tile * 16 + nIdx];
                b[j] = (short)f2bf(v);
            }
            B[tile][t] = b;
        }
    }

    for (int tileR = blockIdx.x; tileR < N_NODES / 16; tileR += gridDim.x) {
        const int rowbase = tileR * 16;
        const unsigned short* ap = xb + (size_t)(rowbase + nIdx) * D + q * 8;
        const short8 A0 = *(const short8*)(ap);
        const short8 A1 = *(const short8*)(ap + 32);
        const short8 A2 = *(const short8*)(ap + 64);
        const short8 A3 = *(const short8*)(ap + 96);

        floatx4 acc0 = {0.f, 0.f, 0.f, 0.f};
        floatx4 acc1 = {0.f, 0.f, 0.f, 0.f};
        acc0 = __builtin_amdgcn_mfma_f32_16x16x32_bf16(A0, B[0][0], acc0, 0, 0, 0);
        acc1 = __builtin_amdgcn_mfma_f32_16x16x32_bf16(A0, B[1][0], acc1, 0, 0, 0);
        acc0 = __builtin_amdgcn_mfma_f32_16x16x32_bf16(A1, B[0][1], acc0, 0, 0, 0);
        acc1 = __builtin_amdgcn_mfma_f32_16x16x32_bf16(A1, B[1][1], acc1, 0, 0, 0);
        acc0 = __builtin_amdgcn_mfma_f32_16x16x32_bf16(A2, B[0][2], acc0, 0, 0, 0);
        acc1 = __builtin_amdgcn_mfma_f32_16x16x32_bf16(A2, B[1][2], acc1, 0, 0, 0);
        acc0 = __builtin_amdgcn_mfma_f32_16x16x32_bf16(A3, B[0][3], acc0, 0, 0, 0);
        acc1 = __builtin_amdgcn_mfma_f32_16x16x32_bf16(A3, B[1][3], acc1, 0, 0, 0);

        #pragma unroll
        for (int i = 0; i < 4; ++i) {
            const int row = rowbase + q * 4 + i;
            hb[(size_t)row * D + n0 + nIdx]      = (unsigned short)f2bf(acc0[i]);
            hb[(size_t)row * D + n0 + 16 + nIdx] = (unsigned short)f2bf(acc1[i]);
        }
    }

    // deg count tail: fire-and-forget atomics overlap other waves' MFMA.
    const int gid = blockIdx.x * blockDim.x + threadIdx.x;
    const int nt = gridDim.x * blockDim.x;
    const int* dst = ei + N_EDGES;
    for (int e = gid; e < N_EDGES; e += nt)
        atomicAdd(&deg[dst[e]], 1);
}

__device__ __forceinline__ void online_combine(float& m, float& s,
                                               float om, float os)
{
    float nm = fmaxf(m, om);
    s = s * __expf(m - nm) + os * __expf(om - nm);
    m = nm;
}

// ---- two-level scan: A) block sums, B) scan of partials, C) local scan+add
__global__ __launch_bounds__(256) void k_scan_a(
    const int* __restrict__ deg, int* __restrict__ partials)
{
    const int i = blockIdx.x * 256 + threadIdx.x;
    int v = (i < N_NODES) ? deg[i] : 0;
    #pragma unroll
    for (int off = 32; off >= 1; off >>= 1) v += __shfl_down(v, off);
    __shared__ int ws[4];
    if ((threadIdx.x & 63) == 0) ws[threadIdx.x >> 6] = v;
    __syncthreads();
    if (threadIdx.x == 0)
        partials[blockIdx.x] = ws[0] + ws[1] + ws[2] + ws[3];
}

__global__ __launch_bounds__(256) void k_scan_b(
    const int* __restrict__ partials, int* __restrict__ partialOffs,
    int* __restrict__ offs)
{
    __shared__ int sc[256];
    const int t = threadIdx.x;
    int v = (t < NSCAN_BLOCKS) ? partials[t] : 0;
    sc[t] = v;
    __syncthreads();
    #pragma unroll
    for (int off = 1; off < 256; off <<= 1) {
        int u = (t >= off) ? sc[t - off] : 0;
        __syncthreads();
        sc[t] += u;
        __syncthreads();
    }
    if (t < NSCAN_BLOCKS) partialOffs[t] = sc[t] - v;   // exclusive
    if (t == 255) offs[N_NODES] = sc[255];              // == N_EDGES
}

__global__ __launch_bounds__(256) void k_scan_c(
    const int* __restrict__ deg, const int* __restrict__ partialOffs,
    int* __restrict__ offs, int* __restrict__ cursor)
{
    __shared__ int sc[256];
    const int t = threadIdx.x;
    const int i = blockIdx.x * 256 + t;
    const int v = (i < N_NODES) ? deg[i] : 0;
    sc[t] = v;
    __syncthreads();
    #pragma unroll
    for (int off = 1; off < 256; off <<= 1) {
        int u = (t >= off) ? sc[t - off] : 0;
        __syncthreads();
        sc[t] += u;
        __syncthreads();
    }
    if (i < N_NODES) {
        const int o = partialOffs[blockIdx.x] + sc[t] - v;  // exclusive
        offs[i] = o;
        cursor[i] = o;
    }
}

// ---- K-bucket: scatter (src, e-score) into dst-sorted CSR, fused with the
// global online-softmax (m, sumexp) block reduction.
__global__ __launch_bounds__(256) void k_bucket(
    const int* __restrict__ ei, const float* __restrict__ s1,
    const float* __restrict__ s2, int* __restrict__ cursor,
    int2* __restrict__ csr, float* __restrict__ bm, float* __restrict__ bs)
{
    const int* src = ei;
    const int* dst = ei + N_EDGES;
    float m = NEG_INF, s = 0.f;
    for (int e = blockIdx.x * blockDim.x + threadIdx.x; e < N_EDGES;
         e += blockDim.x * gridDim.x) {
        const int sN = src[e];
        const int dN = dst[e];
        float v = s1[sN] + s2[dN];
        v = v > 0.f ? v : ALPHA * v;
        const int pos = atomicAdd(&cursor[dN], 1);
        csr[pos] = make_int2(sN, __float_as_int(v));
        float nm = fmaxf(m, v);
        s = s * __expf(m - nm) + __expf(v - nm);
        m = nm;
    }
    #pragma unroll
    for (int off = 32; off >= 1; off >>= 1) {
        float om = __shfl_down(m, off);
        float os = __shfl_down(s, off);
        online_combine(m, s, om, os);
    }
    __shared__ float rm[4], rs[4];
    const int wid = threadIdx.x >> 6;
    if ((threadIdx.x & 63) == 0) { rm[wid] = m; rs[wid] = s; }
    __syncthreads();
    if (threadIdx.x == 0) {
        #pragma unroll
        for (int w = 1; w < 4; ++w) online_combine(m, s, rm[w], rs[w]);
        bm[blockIdx.x] = m;
        bs[blockIdx.x] = s;
    }
}

// ---- reduce per-block (m,s) -> global (M, Z)
__global__ __launch_bounds__(256) void k_reduce_mz(
    const float* __restrict__ bm, const float* __restrict__ bs,
    float* __restrict__ MZ)
{
    float m = NEG_INF, s = 0.f;
    for (int i = threadIdx.x; i < KB_BLOCKS; i += 256)
        online_combine(m, s, bm[i], bs[i]);
    #pragma unroll
    for (int off = 32; off >= 1; off >>= 1) {
        float om = __shfl_down(m, off);
        float os = __shfl_down(s, off);
        online_combine(m, s, om, os);
    }
    __shared__ float rm[4], rs[4];
    const int wid = threadIdx.x >> 6;
    if ((threadIdx.x & 63) == 0) { rm[wid] = m; rs[wid] = s; }
    __syncthreads();
    if (threadIdx.x == 0) {
        #pragma unroll
        for (int w = 1; w < 4; ++w) online_combine(m, s, rm[w], rs[w]);
        MZ[0] = m;
        MZ[1] = s;
    }
}

// ---- K-gather: one wave per dst node. Each lane loads ONE csr entry
// (coalesced) and computes ONE exp; inner loop broadcasts (src, att) via
// uniform-index shfl (readlane) and keeps 4 hb row loads in flight.
__global__ __launch_bounds__(256) void k_gather(
    const int2* __restrict__ csr, const int* __restrict__ offs,
    const unsigned short* __restrict__ hb, const float* __restrict__ MZ,
    float* __restrict__ out)
{
    const int node = (blockIdx.x * blockDim.x + threadIdx.x) >> 6;
    if (node >= N_NODES) return;
    const int lane = threadIdx.x & 63;
    const float M = MZ[0];
    const float invZ = 1.0f / MZ[1];
    const int beg = offs[node];
    const int end = offs[node + 1];

    float a0 = 0.f, a1 = 0.f, b0 = 0.f, b1 = 0.f;
    float c0 = 0.f, c1 = 0.f, d0 = 0.f, d1 = 0.f;

    for (int cb = beg; cb < end; cb += 64) {
        const int n = min(64, end - cb);
        int2 p = make_int2(0, __float_as_int(NEG_INF));
        if (cb + lane < end) p = csr[cb + lane];
        const int srcl = p.x;
        const float attl = __expf(__int_as_float(p.y) - M) * invZ;

        int j = 0;
        for (; j + 3 < n; j += 4) {
            const int i0 = __shfl(srcl, j);
            const int i1 = __shfl(srcl, j + 1);
            const int i2 = __shfl(srcl, j + 2);
            const int i3 = __shfl(srcl, j + 3);
            const float w0 = __shfl(attl, j);
            const float w1 = __shfl(attl, j + 1);
            const float w2 = __shfl(attl, j + 2);
            const float w3 = __shfl(attl, j + 3);
            const unsigned int u0 =
                *(const unsigned int*)(hb + (size_t)i0 * D + lane * 2);
            const unsigned int u1 =
                *(const unsigned int*)(hb + (size_t)i1 * D + lane * 2);
            const unsigned int u2 =
                *(const unsigned int*)(hb + (size_t)i2 * D + lane * 2);
            const unsigned int u3 =
                *(const unsigned int*)(hb + (size_t)i3 * D + lane * 2);
            a0 += w0 * bf_lo(u0); a1 += w0 * bf_hi(u0);
            b0 += w1 * bf_lo(u1); b1 += w1 * bf_hi(u1);
            c0 += w2 * bf_lo(u2); c1 += w2 * bf_hi(u2);
            d0 += w3 * bf_lo(u3); d1 += w3 * bf_hi(u3);
        }
        for (; j < n; ++j) {
            const int i0 = __shfl(srcl, j);
            const float w0 = __shfl(attl, j);
            const unsigned int u0 =
                *(const unsigned int*)(hb + (size_t)i0 * D + lane * 2);
            a0 += w0 * bf_lo(u0); a1 += w0 * bf_hi(u0);
        }
    }
    float2 r;
    r.x = (a0 + b0) + (c0 + d0);
    r.y = (a1 + b1) + (c1 + d1);
    *(float2*)(out + (size_t)node * D + lane * 2) = r;
}

extern "C" void kernel_launch(void* const* d_in, const int* in_sizes, int n_in,
                              void* d_out, int out_size, void* d_ws, size_t ws_size,
                              hipStream_t stream)
{
    const float* x = (const float*)d_in[0];
    const float* W = (const float*)d_in[1];
    const float* a = (const float*)d_in[2];
    const int* ei = (const int*)d_in[3];
    float* out = (float*)d_out;

    // workspace layout; xb and csr share the first region (disjoint lifetimes:
    // xb dead after k_gemm_mfma, csr born in k_bucket).
    char* wsb = (char*)d_ws;
    unsigned short* xb = (unsigned short*)wsb;                     // 12.8 MB
    int2* csr = (int2*)wsb;                                        // 6.4 MB (union)
    unsigned short* hb = (unsigned short*)(wsb + (size_t)N_NODES * D * 2); // 12.8 MB
    float* s1     = (float*)((char*)hb + (size_t)N_NODES * D * 2); // 50,000
    float* s2     = s1 + N_NODES;                                  // 50,000
    int*   deg    = (int*)(s2 + N_NODES);                          // 50,000
    int*   offs   = deg + N_NODES;                                 // 50,001
    int*   cursor = offs + N_NODES + 1;                            // 50,000
    int*   partials    = cursor + N_NODES;                         // 196
    int*   partialOffs = partials + NSCAN_BLOCKS;                  // 196
    float* w12    = (float*)(partialOffs + NSCAN_BLOCKS);          // 256
    float* bm     = w12 + 2 * D;                                   // 1024
    float* bs     = bm + KB_BLOCKS;                                // 1024
    float* MZ     = bs + KB_BLOCKS;                                // 2

    hipMemsetAsync(deg, 0, N_NODES * sizeof(int), stream);

    k_wprep<<<1, 256, 0, stream>>>(W, a, w12);
    k_cast<<<KC_BLOCKS, 256, 0, stream>>>(x, w12, xb, s1, s2);
    k_gemm_mfma<<<512, 256, 0, stream>>>(xb, W, hb, ei, deg);
    k_scan_a<<<NSCAN_BLOCKS, 256, 0, stream>>>(deg, partials);
    k_scan_b<<<1, 256, 0, stream>>>(partials, partialOffs, offs);
    k_scan_c<<<NSCAN_BLOCKS, 256, 0, stream>>>(deg, partialOffs, offs, cursor);
    k_bucket<<<KB_BLOCKS, 256, 0, stream>>>(ei, s1, s2, cursor, csr, bm, bs);
    k_reduce_mz<<<1, 256, 0, stream>>>(bm, bs, MZ);
    k_gather<<<(N_NODES * 64 + 255) / 256, 256, 0, stream>>>(
        csr, offs, hb, MZ, out);
}

// Round 8
// 207.627 us; speedup vs baseline: 7.6920x; 1.0679x over previous
//
#include <hip/hip_runtime.h>
#include <hip/hip_bf16.h>

#define N_NODES 50000
#define N_EDGES 800000
#define D 128
#define ALPHA 0.2f
#define NEG_INF -1e30f

#define KB_BLOCKS 1024
#define NSCAN_BLOCKS ((N_NODES + 255) / 256)   // 196
#define LDS_STRIDE 272                          // 16 rows x (256B + 16B pad)

typedef __attribute__((ext_vector_type(8))) short short8;
typedef __attribute__((ext_vector_type(4))) float floatx4;

__device__ __forceinline__ unsigned int f2bf(float v)
{
    __hip_bfloat16 b = __float2bfloat16(v);
    return (unsigned int)*reinterpret_cast<unsigned short*>(&b);
}
__device__ __forceinline__ float bf_lo(unsigned int u)
{
    return __uint_as_float(u << 16);
}
__device__ __forceinline__ float bf_hi(unsigned int u)
{
    return __uint_as_float(u & 0xFFFF0000u);
}

// ---- K0: w12[0:128)=W@a1, w12[128:256)=W@a2 (fp32, exact factorization)
__global__ __launch_bounds__(256) void k_wprep(
    const float* __restrict__ W, const float* __restrict__ a,
    float* __restrict__ w12)
{
    const int t = threadIdx.x;
    const int i = t & 127;
    const int which = t >> 7;
    const float* av = a + which * D;
    float acc = 0.f;
    #pragma unroll 8
    for (int j = 0; j < D; ++j)
        acc += W[(size_t)i * D + j] * av[j];
    w12[which * D + i] = acc;
}

// ---- K1: fused per-16-row-tile kernel, 3125 blocks (exact):
//   (a) load x tile fp32, exact s1/s2 (16-lane xor-reduce), bf16 -> LDS
//   (b) per-wave B frags from W, even/odd column split
//   (c) 8x MFMA 16x16x32 bf16, packed u32 stores of hb
//   (d) deg count: exactly 1 edge per thread (3125*256 == N_EDGES)
__global__ __launch_bounds__(256) void k_fused(
    const float* __restrict__ x, const float* __restrict__ W,
    const float* __restrict__ w12, const int* __restrict__ ei,
    unsigned short* __restrict__ hb, float* __restrict__ s1,
    float* __restrict__ s2, int* __restrict__ deg)
{
    __shared__ unsigned char lds[16 * LDS_STRIDE];
    const int t = threadIdx.x;
    const int rowbase = blockIdx.x * 16;

    // (a) stage x: thread t -> row r=t>>4, col-group c=t&15 (8 cols)
    const int r = t >> 4;
    const int c = t & 15;
    const float* xp = x + (size_t)(rowbase + r) * D + c * 8;
    const float4 v0 = *(const float4*)(xp);
    const float4 v1 = *(const float4*)(xp + 4);

    // (b) B frags — issue independent of staging loads
    const int lane = t & 63;
    const int wv = t >> 6;
    const int q = lane >> 4;
    const int nIdx = lane & 15;
    const int n0 = wv * 32;
    short8 B[2][4];
    #pragma unroll
    for (int kt = 0; kt < 4; ++kt) {
        short8 be, bo;
        #pragma unroll
        for (int j = 0; j < 8; ++j) {
            const float* wp = W + (size_t)(kt * 32 + q * 8 + j) * D + n0 + 2 * nIdx;
            be[j] = (short)f2bf(wp[0]);
            bo[j] = (short)f2bf(wp[1]);
        }
        B[0][kt] = be;
        B[1][kt] = bo;
    }

    // (a cont.) s1/s2 exact fp32 partials + bf16 pack to LDS
    {
        const float* w1 = w12 + c * 8;
        const float* w2 = w12 + D + c * 8;
        float p1 = v0.x * w1[0] + v0.y * w1[1] + v0.z * w1[2] + v0.w * w1[3]
                 + v1.x * w1[4] + v1.y * w1[5] + v1.z * w1[6] + v1.w * w1[7];
        float p2 = v0.x * w2[0] + v0.y * w2[1] + v0.z * w2[2] + v0.w * w2[3]
                 + v1.x * w2[4] + v1.y * w2[5] + v1.z * w2[6] + v1.w * w2[7];
        #pragma unroll
        for (int mask = 8; mask >= 1; mask >>= 1) {
            p1 += __shfl_xor(p1, mask);
            p2 += __shfl_xor(p2, mask);
        }
        if (c == 0) { s1[rowbase + r] = p1; s2[rowbase + r] = p2; }

        uint4 pk;
        pk.x = f2bf(v0.x) | (f2bf(v0.y) << 16);
        pk.y = f2bf(v0.z) | (f2bf(v0.w) << 16);
        pk.z = f2bf(v1.x) | (f2bf(v1.y) << 16);
        pk.w = f2bf(v1.z) | (f2bf(v1.w) << 16);
        *(uint4*)(lds + r * LDS_STRIDE + c * 16) = pk;
    }
    __syncthreads();

    // (c) A frags from LDS: A[m=nIdx][k=kt*32+q*8+j] -> byte kt*64 + q*16
    const unsigned char* ab = lds + nIdx * LDS_STRIDE + q * 16;
    const short8 A0 = *(const short8*)(ab);
    const short8 A1 = *(const short8*)(ab + 64);
    const short8 A2 = *(const short8*)(ab + 128);
    const short8 A3 = *(const short8*)(ab + 192);

    floatx4 acc0 = {0.f, 0.f, 0.f, 0.f};
    floatx4 acc1 = {0.f, 0.f, 0.f, 0.f};
    acc0 = __builtin_amdgcn_mfma_f32_16x16x32_bf16(A0, B[0][0], acc0, 0, 0, 0);
    acc1 = __builtin_amdgcn_mfma_f32_16x16x32_bf16(A0, B[1][0], acc1, 0, 0, 0);
    acc0 = __builtin_amdgcn_mfma_f32_16x16x32_bf16(A1, B[0][1], acc0, 0, 0, 0);
    acc1 = __builtin_amdgcn_mfma_f32_16x16x32_bf16(A1, B[1][1], acc1, 0, 0, 0);
    acc0 = __builtin_amdgcn_mfma_f32_16x16x32_bf16(A2, B[0][2], acc0, 0, 0, 0);
    acc1 = __builtin_amdgcn_mfma_f32_16x16x32_bf16(A2, B[1][2], acc1, 0, 0, 0);
    acc0 = __builtin_amdgcn_mfma_f32_16x16x32_bf16(A3, B[0][3], acc0, 0, 0, 0);
    acc1 = __builtin_amdgcn_mfma_f32_16x16x32_bf16(A3, B[1][3], acc1, 0, 0, 0);

    // epilogue: acc0 = even col n0+2*nIdx, acc1 = odd col n0+2*nIdx+1
    #pragma unroll
    for (int i = 0; i < 4; ++i) {
        const int row = rowbase + q * 4 + i;
        const unsigned int pk = f2bf(acc0[i]) | (f2bf(acc1[i]) << 16);
        *(unsigned int*)(hb + (size_t)row * D + n0 + 2 * nIdx) = pk;
    }

    // (d) deg: exactly one edge per thread
    const int e = blockIdx.x * 256 + t;
    atomicAdd(&deg[ei[N_EDGES + e]], 1);
}

__device__ __forceinline__ void online_combine(float& m, float& s,
                                               float om, float os)
{
    float nm = fmaxf(m, om);
    s = s * __expf(m - nm) + os * __expf(om - nm);
    m = nm;
}

// ---- two-level scan: A) block sums, B) scan of partials, C) local scan+add
__global__ __launch_bounds__(256) void k_scan_a(
    const int* __restrict__ deg, int* __restrict__ partials)
{
    const int i = blockIdx.x * 256 + threadIdx.x;
    int v = (i < N_NODES) ? deg[i] : 0;
    #pragma unroll
    for (int off = 32; off >= 1; off >>= 1) v += __shfl_down(v, off);
    __shared__ int ws[4];
    if ((threadIdx.x & 63) == 0) ws[threadIdx.x >> 6] = v;
    __syncthreads();
    if (threadIdx.x == 0)
        partials[blockIdx.x] = ws[0] + ws[1] + ws[2] + ws[3];
}

__global__ __launch_bounds__(256) void k_scan_b(
    const int* __restrict__ partials, int* __restrict__ partialOffs,
    int* __restrict__ offs)
{
    __shared__ int sc[256];
    const int t = threadIdx.x;
    int v = (t < NSCAN_BLOCKS) ? partials[t] : 0;
    sc[t] = v;
    __syncthreads();
    #pragma unroll
    for (int off = 1; off < 256; off <<= 1) {
        int u = (t >= off) ? sc[t - off] : 0;
        __syncthreads();
        sc[t] += u;
        __syncthreads();
    }
    if (t < NSCAN_BLOCKS) partialOffs[t] = sc[t] - v;   // exclusive
    if (t == 255) offs[N_NODES] = sc[255];              // == N_EDGES
}

__global__ __launch_bounds__(256) void k_scan_c(
    const int* __restrict__ deg, const int* __restrict__ partialOffs,
    int* __restrict__ offs, int* __restrict__ cursor)
{
    __shared__ int sc[256];
    const int t = threadIdx.x;
    const int i = blockIdx.x * 256 + t;
    const int v = (i < N_NODES) ? deg[i] : 0;
    sc[t] = v;
    __syncthreads();
    #pragma unroll
    for (int off = 1; off < 256; off <<= 1) {
        int u = (t >= off) ? sc[t - off] : 0;
        __syncthreads();
        sc[t] += u;
        __syncthreads();
    }
    if (i < N_NODES) {
        const int o = partialOffs[blockIdx.x] + sc[t] - v;  // exclusive
        offs[i] = o;
        cursor[i] = o;
    }
}

// ---- K-bucket: scatter (src, e-score) into dst-sorted CSR, fused with the
// global online-softmax (m, sumexp) block reduction.
__global__ __launch_bounds__(256) void k_bucket(
    const int* __restrict__ ei, const float* __restrict__ s1,
    const float* __restrict__ s2, int* __restrict__ cursor,
    int2* __restrict__ csr, float* __restrict__ bm, float* __restrict__ bs)
{
    const int* src = ei;
    const int* dst = ei + N_EDGES;
    float m = NEG_INF, s = 0.f;
    for (int e = blockIdx.x * blockDim.x + threadIdx.x; e < N_EDGES;
         e += blockDim.x * gridDim.x) {
        const int sN = src[e];
        const int dN = dst[e];
        float v = s1[sN] + s2[dN];
        v = v > 0.f ? v : ALPHA * v;
        const int pos = atomicAdd(&cursor[dN], 1);
        csr[pos] = make_int2(sN, __float_as_int(v));
        float nm = fmaxf(m, v);
        s = s * __expf(m - nm) + __expf(v - nm);
        m = nm;
    }
    #pragma unroll
    for (int off = 32; off >= 1; off >>= 1) {
        float om = __shfl_down(m, off);
        float os = __shfl_down(s, off);
        online_combine(m, s, om, os);
    }
    __shared__ float rm[4], rs[4];
    const int wid = threadIdx.x >> 6;
    if ((threadIdx.x & 63) == 0) { rm[wid] = m; rs[wid] = s; }
    __syncthreads();
    if (threadIdx.x == 0) {
        #pragma unroll
        for (int w = 1; w < 4; ++w) online_combine(m, s, rm[w], rs[w]);
        bm[blockIdx.x] = m;
        bs[blockIdx.x] = s;
    }
}

// ---- reduce per-block (m,s) -> global (M, Z)
__global__ __launch_bounds__(256) void k_reduce_mz(
    const float* __restrict__ bm, const float* __restrict__ bs,
    float* __restrict__ MZ)
{
    float m = NEG_INF, s = 0.f;
    for (int i = threadIdx.x; i < KB_BLOCKS; i += 256)
        online_combine(m, s, bm[i], bs[i]);
    #pragma unroll
    for (int off = 32; off >= 1; off >>= 1) {
        float om = __shfl_down(m, off);
        float os = __shfl_down(s, off);
        online_combine(m, s, om, os);
    }
    __shared__ float rm[4], rs[4];
    const int wid = threadIdx.x >> 6;
    if ((threadIdx.x & 63) == 0) { rm[wid] = m; rs[wid] = s; }
    __syncthreads();
    if (threadIdx.x == 0) {
        #pragma unroll
        for (int w = 1; w < 4; ++w) online_combine(m, s, rm[w], rs[w]);
        MZ[0] = m;
        MZ[1] = s;
    }
}

// ---- K-gather: one wave per dst node. Each lane loads ONE csr entry
// (coalesced) and computes ONE exp; inner loop broadcasts (src, att) via
// uniform-index shfl (readlane) and keeps 4 hb row loads in flight.
__global__ __launch_bounds__(256) void k_gather(
    const int2* __restrict__ csr, const int* __restrict__ offs,
    const unsigned short* __restrict__ hb, const float* __restrict__ MZ,
    float* __restrict__ out)
{
    const int node = (blockIdx.x * blockDim.x + threadIdx.x) >> 6;
    if (node >= N_NODES) return;
    const int lane = threadIdx.x & 63;
    const float M = MZ[0];
    const float invZ = 1.0f / MZ[1];
    const int beg = offs[node];
    const int end = offs[node + 1];

    float a0 = 0.f, a1 = 0.f, b0 = 0.f, b1 = 0.f;
    float c0 = 0.f, c1 = 0.f, d0 = 0.f, d1 = 0.f;

    for (int cb = beg; cb < end; cb += 64) {
        const int n = min(64, end - cb);
        int2 p = make_int2(0, __float_as_int(NEG_INF));
        if (cb + lane < end) p = csr[cb + lane];
        const int srcl = p.x;
        const float attl = __expf(__int_as_float(p.y) - M) * invZ;

        int j = 0;
        for (; j + 3 < n; j += 4) {
            const int i0 = __shfl(srcl, j);
            const int i1 = __shfl(srcl, j + 1);
            const int i2 = __shfl(srcl, j + 2);
            const int i3 = __shfl(srcl, j + 3);
            const float w0 = __shfl(attl, j);
            const float w1 = __shfl(attl, j + 1);
            const float w2 = __shfl(attl, j + 2);
            const float w3 = __shfl(attl, j + 3);
            const unsigned int u0 =
                *(const unsigned int*)(hb + (size_t)i0 * D + lane * 2);
            const unsigned int u1 =
                *(const unsigned int*)(hb + (size_t)i1 * D + lane * 2);
            const unsigned int u2 =
                *(const unsigned int*)(hb + (size_t)i2 * D + lane * 2);
            const unsigned int u3 =
                *(const unsigned int*)(hb + (size_t)i3 * D + lane * 2);
            a0 += w0 * bf_lo(u0); a1 += w0 * bf_hi(u0);
            b0 += w1 * bf_lo(u1); b1 += w1 * bf_hi(u1);
            c0 += w2 * bf_lo(u2); c1 += w2 * bf_hi(u2);
            d0 += w3 * bf_lo(u3); d1 += w3 * bf_hi(u3);
        }
        for (; j < n; ++j) {
            const int i0 = __shfl(srcl, j);
            const float w0 = __shfl(attl, j);
            const unsigned int u0 =
                *(const unsigned int*)(hb + (size_t)i0 * D + lane * 2);
            a0 += w0 * bf_lo(u0); a1 += w0 * bf_hi(u0);
        }
    }
    float2 r;
    r.x = (a0 + b0) + (c0 + d0);
    r.y = (a1 + b1) + (c1 + d1);
    *(float2*)(out + (size_t)node * D + lane * 2) = r;
}

extern "C" void kernel_launch(void* const* d_in, const int* in_sizes, int n_in,
                              void* d_out, int out_size, void* d_ws, size_t ws_size,
                              hipStream_t stream)
{
    const float* x = (const float*)d_in[0];
    const float* W = (const float*)d_in[1];
    const float* a = (const float*)d_in[2];
    const int* ei = (const int*)d_in[3];
    float* out = (float*)d_out;

    char* wsb = (char*)d_ws;
    int2* csr = (int2*)wsb;                                        // 6.4 MB
    unsigned short* hb = (unsigned short*)(wsb + (size_t)N_EDGES * 8); // 12.8 MB
    float* s1     = (float*)((char*)hb + (size_t)N_NODES * D * 2); // 50,000
    float* s2     = s1 + N_NODES;                                  // 50,000
    int*   deg    = (int*)(s2 + N_NODES);                          // 50,000
    int*   offs   = deg + N_NODES;                                 // 50,001
    int*   cursor = offs + N_NODES + 1;                            // 50,000
    int*   partials    = cursor + N_NODES;                         // 196
    int*   partialOffs = partials + NSCAN_BLOCKS;                  // 196
    float* w12    = (float*)(partialOffs + NSCAN_BLOCKS);          // 256
    float* bm     = w12 + 2 * D;                                   // 1024
    float* bs     = bm + KB_BLOCKS;                                // 1024
    float* MZ     = bs + KB_BLOCKS;                                // 2

    hipMemsetAsync(deg, 0, N_NODES * sizeof(int), stream);

    k_wprep<<<1, 256, 0, stream>>>(W, a, w12);
    k_fused<<<N_NODES / 16, 256, 0, stream>>>(x, W, w12, ei, hb, s1, s2, deg);
    k_scan_a<<<NSCAN_BLOCKS, 256, 0, stream>>>(deg, partials);
    k_scan_b<<<1, 256, 0, stream>>>(partials, partialOffs, offs);
    k_scan_c<<<NSCAN_BLOCKS, 256, 0, stream>>>(deg, partialOffs, offs, cursor);
    k_bucket<<<KB_BLOCKS, 256, 0, stream>>>(ei, s1, s2, cursor, csr, bm, bs);
    k_reduce_mz<<<1, 256, 0, stream>>>(bm, bs, MZ);
    k_gather<<<(N_NODES * 64 + 255) / 256, 256, 0, stream>>>(
        csr, offs, hb, MZ, out);
}

// Round 9
// 186.791 us; speedup vs baseline: 8.5500x; 1.1115x over previous
//
#include <hip/hip_runtime.h>
#include <hip/hip_bf16.h>

#define N_NODES 50000
#define N_EDGES 800000
#define D 128
#define ALPHA 0.2f
#define NEG_INF -1e30f

#define KB_BLOCKS 3125                          // 1 edge per thread, exact
#define NSCAN_BLOCKS ((N_NODES + 255) / 256)   // 196
#define LDS_STRIDE 272                          // 16 rows x (256B + 16B pad)

typedef __attribute__((ext_vector_type(8))) short short8;
typedef __attribute__((ext_vector_type(4))) float floatx4;

__device__ __forceinline__ unsigned int f2bf(float v)
{
    __hip_bfloat16 b = __float2bfloat16(v);
    return (unsigned int)*reinterpret_cast<unsigned short*>(&b);
}
__device__ __forceinline__ float bf_lo(unsigned int u)
{
    return __uint_as_float(u << 16);
}
__device__ __forceinline__ float bf_hi(unsigned int u)
{
    return __uint_as_float(u & 0xFFFF0000u);
}

// ---- K0: w12[0:128)=W@a1, w12[128:256)=W@a2 (fp32, exact factorization)
__global__ __launch_bounds__(256) void k_wprep(
    const float* __restrict__ W, const float* __restrict__ a,
    float* __restrict__ w12)
{
    const int t = threadIdx.x;
    const int i = t & 127;
    const int which = t >> 7;
    const float* av = a + which * D;
    float acc = 0.f;
    #pragma unroll 8
    for (int j = 0; j < D; ++j)
        acc += W[(size_t)i * D + j] * av[j];
    w12[which * D + i] = acc;
}

// ---- K1: fused per-16-row-tile kernel, 3125 blocks (exact):
//   (a) load x tile fp32, exact s1/s2 (16-lane xor-reduce), bf16 -> LDS
//   (b) per-wave B frags from W, even/odd column split
//   (c) 8x MFMA 16x16x32 bf16, packed u32 stores of hb
//   (d) deg count + per-edge rank (atomic return), 1 edge per thread
__global__ __launch_bounds__(256) void k_fused(
    const float* __restrict__ x, const float* __restrict__ W,
    const float* __restrict__ w12, const int* __restrict__ ei,
    unsigned short* __restrict__ hb, float* __restrict__ s1,
    float* __restrict__ s2, int* __restrict__ deg, int* __restrict__ rank)
{
    __shared__ unsigned char lds[16 * LDS_STRIDE];
    const int t = threadIdx.x;
    const int rowbase = blockIdx.x * 16;

    // (a) stage x: thread t -> row r=t>>4, col-group c=t&15 (8 cols)
    const int r = t >> 4;
    const int c = t & 15;
    const float* xp = x + (size_t)(rowbase + r) * D + c * 8;
    const float4 v0 = *(const float4*)(xp);
    const float4 v1 = *(const float4*)(xp + 4);

    // (b) B frags — issue independent of staging loads
    const int lane = t & 63;
    const int wv = t >> 6;
    const int q = lane >> 4;
    const int nIdx = lane & 15;
    const int n0 = wv * 32;
    short8 B[2][4];
    #pragma unroll
    for (int kt = 0; kt < 4; ++kt) {
        short8 be, bo;
        #pragma unroll
        for (int j = 0; j < 8; ++j) {
            const float* wp = W + (size_t)(kt * 32 + q * 8 + j) * D + n0 + 2 * nIdx;
            be[j] = (short)f2bf(wp[0]);
            bo[j] = (short)f2bf(wp[1]);
        }
        B[0][kt] = be;
        B[1][kt] = bo;
    }

    // (a cont.) s1/s2 exact fp32 partials + bf16 pack to LDS
    {
        const float* w1 = w12 + c * 8;
        const float* w2 = w12 + D + c * 8;
        float p1 = v0.x * w1[0] + v0.y * w1[1] + v0.z * w1[2] + v0.w * w1[3]
                 + v1.x * w1[4] + v1.y * w1[5] + v1.z * w1[6] + v1.w * w1[7];
        float p2 = v0.x * w2[0] + v0.y * w2[1] + v0.z * w2[2] + v0.w * w2[3]
                 + v1.x * w2[4] + v1.y * w2[5] + v1.z * w2[6] + v1.w * w2[7];
        #pragma unroll
        for (int mask = 8; mask >= 1; mask >>= 1) {
            p1 += __shfl_xor(p1, mask);
            p2 += __shfl_xor(p2, mask);
        }
        if (c == 0) { s1[rowbase + r] = p1; s2[rowbase + r] = p2; }

        uint4 pk;
        pk.x = f2bf(v0.x) | (f2bf(v0.y) << 16);
        pk.y = f2bf(v0.z) | (f2bf(v0.w) << 16);
        pk.z = f2bf(v1.x) | (f2bf(v1.y) << 16);
        pk.w = f2bf(v1.z) | (f2bf(v1.w) << 16);
        *(uint4*)(lds + r * LDS_STRIDE + c * 16) = pk;
    }
    __syncthreads();

    // (c) A frags from LDS: A[m=nIdx][k=kt*32+q*8+j] -> byte kt*64 + q*16
    const unsigned char* ab = lds + nIdx * LDS_STRIDE + q * 16;
    const short8 A0 = *(const short8*)(ab);
    const short8 A1 = *(const short8*)(ab + 64);
    const short8 A2 = *(const short8*)(ab + 128);
    const short8 A3 = *(const short8*)(ab + 192);

    floatx4 acc0 = {0.f, 0.f, 0.f, 0.f};
    floatx4 acc1 = {0.f, 0.f, 0.f, 0.f};
    acc0 = __builtin_amdgcn_mfma_f32_16x16x32_bf16(A0, B[0][0], acc0, 0, 0, 0);
    acc1 = __builtin_amdgcn_mfma_f32_16x16x32_bf16(A0, B[1][0], acc1, 0, 0, 0);
    acc0 = __builtin_amdgcn_mfma_f32_16x16x32_bf16(A1, B[0][1], acc0, 0, 0, 0);
    acc1 = __builtin_amdgcn_mfma_f32_16x16x32_bf16(A1, B[1][1], acc1, 0, 0, 0);
    acc0 = __builtin_amdgcn_mfma_f32_16x16x32_bf16(A2, B[0][2], acc0, 0, 0, 0);
    acc1 = __builtin_amdgcn_mfma_f32_16x16x32_bf16(A2, B[1][2], acc1, 0, 0, 0);
    acc0 = __builtin_amdgcn_mfma_f32_16x16x32_bf16(A3, B[0][3], acc0, 0, 0, 0);
    acc1 = __builtin_amdgcn_mfma_f32_16x16x32_bf16(A3, B[1][3], acc1, 0, 0, 0);

    // epilogue: acc0 = even col n0+2*nIdx, acc1 = odd col n0+2*nIdx+1
    #pragma unroll
    for (int i = 0; i < 4; ++i) {
        const int row = rowbase + q * 4 + i;
        const unsigned int pk = f2bf(acc0[i]) | (f2bf(acc1[i]) << 16);
        *(unsigned int*)(hb + (size_t)row * D + n0 + 2 * nIdx) = pk;
    }

    // (d) deg + rank: exactly one edge per thread (3125*256 == N_EDGES)
    const int e = blockIdx.x * 256 + t;
    rank[e] = atomicAdd(&deg[ei[N_EDGES + e]], 1);
}

__device__ __forceinline__ void online_combine(float& m, float& s,
                                               float om, float os)
{
    float nm = fmaxf(m, om);
    s = s * __expf(m - nm) + os * __expf(om - nm);
    m = nm;
}

// ---- two-level scan: A) block sums, B) scan of partials, C) local scan+add
__global__ __launch_bounds__(256) void k_scan_a(
    const int* __restrict__ deg, int* __restrict__ partials)
{
    const int i = blockIdx.x * 256 + threadIdx.x;
    int v = (i < N_NODES) ? deg[i] : 0;
    #pragma unroll
    for (int off = 32; off >= 1; off >>= 1) v += __shfl_down(v, off);
    __shared__ int ws[4];
    if ((threadIdx.x & 63) == 0) ws[threadIdx.x >> 6] = v;
    __syncthreads();
    if (threadIdx.x == 0)
        partials[blockIdx.x] = ws[0] + ws[1] + ws[2] + ws[3];
}

__global__ __launch_bounds__(256) void k_scan_b(
    const int* __restrict__ partials, int* __restrict__ partialOffs,
    int* __restrict__ offs)
{
    __shared__ int sc[256];
    const int t = threadIdx.x;
    int v = (t < NSCAN_BLOCKS) ? partials[t] : 0;
    sc[t] = v;
    __syncthreads();
    #pragma unroll
    for (int off = 1; off < 256; off <<= 1) {
        int u = (t >= off) ? sc[t - off] : 0;
        __syncthreads();
        sc[t] += u;
        __syncthreads();
    }
    if (t < NSCAN_BLOCKS) partialOffs[t] = sc[t] - v;   // exclusive
    if (t == 255) offs[N_NODES] = sc[255];              // == N_EDGES
}

__global__ __launch_bounds__(256) void k_scan_c(
    const int* __restrict__ deg, const int* __restrict__ partialOffs,
    int* __restrict__ offs)
{
    __shared__ int sc[256];
    const int t = threadIdx.x;
    const int i = blockIdx.x * 256 + t;
    const int v = (i < N_NODES) ? deg[i] : 0;
    sc[t] = v;
    __syncthreads();
    #pragma unroll
    for (int off = 1; off < 256; off <<= 1) {
        int u = (t >= off) ? sc[t - off] : 0;
        __syncthreads();
        sc[t] += u;
        __syncthreads();
    }
    if (i < N_NODES)
        offs[i] = partialOffs[blockIdx.x] + sc[t] - v;  // exclusive
}

// ---- K-bucket: atomic-free scatter of src into dst-sorted CSR
// (pos = offs[dst] + rank[e]), fused with the global online-softmax
// (m, sumexp) block reduction. 1 edge per thread, exact.
__global__ __launch_bounds__(256) void k_bucket(
    const int* __restrict__ ei, const float* __restrict__ s1,
    const float* __restrict__ s2, const int* __restrict__ offs,
    const int* __restrict__ rank, unsigned int* __restrict__ csr,
    float* __restrict__ bm, float* __restrict__ bs)
{
    const int e = blockIdx.x * 256 + threadIdx.x;
    const int sN = ei[e];
    const int dN = ei[N_EDGES + e];
    csr[offs[dN] + rank[e]] = (unsigned int)sN;

    float v = s1[sN] + s2[dN];
    v = v > 0.f ? v : ALPHA * v;

    float m = v, s = 1.f;
    #pragma unroll
    for (int off = 32; off >= 1; off >>= 1) {
        float om = __shfl_down(m, off);
        float os = __shfl_down(s, off);
        online_combine(m, s, om, os);
    }
    __shared__ float rm[4], rs[4];
    const int wid = threadIdx.x >> 6;
    if ((threadIdx.x & 63) == 0) { rm[wid] = m; rs[wid] = s; }
    __syncthreads();
    if (threadIdx.x == 0) {
        #pragma unroll
        for (int w = 1; w < 4; ++w) online_combine(m, s, rm[w], rs[w]);
        bm[blockIdx.x] = m;
        bs[blockIdx.x] = s;
    }
}

// ---- reduce per-block (m,s) -> global (M, Z)
__global__ __launch_bounds__(256) void k_reduce_mz(
    const float* __restrict__ bm, const float* __restrict__ bs,
    float* __restrict__ MZ)
{
    float m = NEG_INF, s = 0.f;
    for (int i = threadIdx.x; i < KB_BLOCKS; i += 256)
        online_combine(m, s, bm[i], bs[i]);
    #pragma unroll
    for (int off = 32; off >= 1; off >>= 1) {
        float om = __shfl_down(m, off);
        float os = __shfl_down(s, off);
        online_combine(m, s, om, os);
    }
    __shared__ float rm[4], rs[4];
    const int wid = threadIdx.x >> 6;
    if ((threadIdx.x & 63) == 0) { rm[wid] = m; rs[wid] = s; }
    __syncthreads();
    if (threadIdx.x == 0) {
        #pragma unroll
        for (int w = 1; w < 4; ++w) online_combine(m, s, rm[w], rs[w]);
        MZ[0] = m;
        MZ[1] = s;
    }
}

// ---- K-gather: one wave per dst node. Each lane loads ONE csr src
// (coalesced), recomputes the exact fp32 score from s1[src]+s2[node]
// (L2-resident tables) and ONE exp; inner loop broadcasts (src, att)
// via uniform-index shfl and keeps 4 hb row loads in flight.
__global__ __launch_bounds__(256) void k_gather(
    const unsigned int* __restrict__ csr, const int* __restrict__ offs,
    const float* __restrict__ s1, const float* __restrict__ s2,
    const unsigned short* __restrict__ hb, const float* __restrict__ MZ,
    float* __restrict__ out)
{
    const int node = (blockIdx.x * blockDim.x + threadIdx.x) >> 6;
    if (node >= N_NODES) return;
    const int lane = threadIdx.x & 63;
    const float M = MZ[0];
    const float invZ = 1.0f / MZ[1];
    const float s2n = s2[node];
    const int beg = offs[node];
    const int end = offs[node + 1];

    float a0 = 0.f, a1 = 0.f, b0 = 0.f, b1 = 0.f;
    float c0 = 0.f, c1 = 0.f, d0 = 0.f, d1 = 0.f;

    for (int cb = beg; cb < end; cb += 64) {
        const int n = min(64, end - cb);
        const int srcl = (cb + lane < end) ? (int)csr[cb + lane] : 0;
        float v = s1[srcl] + s2n;
        v = v > 0.f ? v : ALPHA * v;
        const float attl = __expf(v - M) * invZ;

        int j = 0;
        for (; j + 3 < n; j += 4) {
            const int i0 = __shfl(srcl, j);
            const int i1 = __shfl(srcl, j + 1);
            const int i2 = __shfl(srcl, j + 2);
            const int i3 = __shfl(srcl, j + 3);
            const float w0 = __shfl(attl, j);
            const float w1 = __shfl(attl, j + 1);
            const float w2 = __shfl(attl, j + 2);
            const float w3 = __shfl(attl, j + 3);
            const unsigned int u0 =
                *(const unsigned int*)(hb + (size_t)i0 * D + lane * 2);
            const unsigned int u1 =
                *(const unsigned int*)(hb + (size_t)i1 * D + lane * 2);
            const unsigned int u2 =
                *(const unsigned int*)(hb + (size_t)i2 * D + lane * 2);
            const unsigned int u3 =
                *(const unsigned int*)(hb + (size_t)i3 * D + lane * 2);
            a0 += w0 * bf_lo(u0); a1 += w0 * bf_hi(u0);
            b0 += w1 * bf_lo(u1); b1 += w1 * bf_hi(u1);
            c0 += w2 * bf_lo(u2); c1 += w2 * bf_hi(u2);
            d0 += w3 * bf_lo(u3); d1 += w3 * bf_hi(u3);
        }
        for (; j < n; ++j) {
            const int i0 = __shfl(srcl, j);
            const float w0 = __shfl(attl, j);
            const unsigned int u0 =
                *(const unsigned int*)(hb + (size_t)i0 * D + lane * 2);
            a0 += w0 * bf_lo(u0); a1 += w0 * bf_hi(u0);
        }
    }
    float2 r;
    r.x = (a0 + b0) + (c0 + d0);
    r.y = (a1 + b1) + (c1 + d1);
    *(float2*)(out + (size_t)node * D + lane * 2) = r;
}

extern "C" void kernel_launch(void* const* d_in, const int* in_sizes, int n_in,
                              void* d_out, int out_size, void* d_ws, size_t ws_size,
                              hipStream_t stream)
{
    const float* x = (const float*)d_in[0];
    const float* W = (const float*)d_in[1];
    const float* a = (const float*)d_in[2];
    const int* ei = (const int*)d_in[3];
    float* out = (float*)d_out;

    char* wsb = (char*)d_ws;
    unsigned int* csr = (unsigned int*)wsb;                        // 3.2 MB
    unsigned short* hb = (unsigned short*)(wsb + (size_t)N_EDGES * 4); // 12.8 MB
    int* rank     = (int*)((char*)hb + (size_t)N_NODES * D * 2);   // 3.2 MB
    float* s1     = (float*)(rank + N_EDGES);                      // 50,000
    float* s2     = s1 + N_NODES;                                  // 50,000
    int*   deg    = (int*)(s2 + N_NODES);                          // 50,000
    int*   offs   = deg + N_NODES;                                 // 50,001
    int*   partials    = offs + N_NODES + 1;                       // 196
    int*   partialOffs = partials + NSCAN_BLOCKS;                  // 196
    float* w12    = (float*)(partialOffs + NSCAN_BLOCKS);          // 256
    float* bm     = w12 + 2 * D;                                   // 3125
    float* bs     = bm + KB_BLOCKS;                                // 3125
    float* MZ     = bs + KB_BLOCKS;                                // 2

    hipMemsetAsync(deg, 0, N_NODES * sizeof(int), stream);

    k_wprep<<<1, 256, 0, stream>>>(W, a, w12);
    k_fused<<<N_NODES / 16, 256, 0, stream>>>(x, W, w12, ei, hb, s1, s2,
                                              deg, rank);
    k_scan_a<<<NSCAN_BLOCKS, 256, 0, stream>>>(deg, partials);
    k_scan_b<<<1, 256, 0, stream>>>(partials, partialOffs, offs);
    k_scan_c<<<NSCAN_BLOCKS, 256, 0, stream>>>(deg, partialOffs, offs);
    k_bucket<<<KB_BLOCKS, 256, 0, stream>>>(ei, s1, s2, offs, rank, csr,
                                            bm, bs);
    k_reduce_mz<<<1, 256, 0, stream>>>(bm, bs, MZ);
    k_gather<<<(N_NODES * 64 + 255) / 256, 256, 0, stream>>>(
        csr, offs, s1, s2, hb, MZ, out);
}